// Round 1
// baseline (3042.990 us; speedup 1.0000x reference)
//
#include <hip/hip_runtime.h>
#include <hip/hip_bf16.h>

#define E_ 1024
#define L_ 25
#define S_ 64
#define C_ 128
#define H_ 512
#define NEXP_ 8

// workspace float offsets
#define OFF_G     0            // 128*128
#define OFF_U     16384        // 128
#define OFF_W     16512        // 128
#define OFF_C0    16640        // 1
#define OFF_PEDOT 16704        // 64*64
#define OFF_W1P   20800        // 8*128*512 = 524288
#define OFF_B1P   545088       // 8*512
#define OFF_NOUT  1048576      // 1024*64*128

// ---------------- prep1: G = Wq Wk^T, u/w/c0 bias folds, pedot ----------------
__global__ void prep1(const float* __restrict__ wq, const float* __restrict__ bq,
                      const float* __restrict__ wk, const float* __restrict__ bk,
                      const float* __restrict__ pe, float* __restrict__ ws) {
    int b = blockIdx.x, tid = threadIdx.x;
    if (b < 64) {
        int a = b * 2 + (tid >> 7);
        int col = tid & 127;
        const float* ra = wq + a * C_;
        const float* rb = wk + col * C_;
        float acc = 0.f;
        for (int c = 0; c < C_; ++c) acc += ra[c] * rb[c];
        ws[OFF_G + a * C_ + col] = acc;
    } else {
        if (tid < 128) {
            float acc = 0.f; const float* r = wq + tid * C_;
            for (int c = 0; c < C_; ++c) acc += r[c] * bk[c];
            ws[OFF_U + tid] = acc;
        } else {
            int j = tid - 128;
            float acc = 0.f; const float* r = wk + j * C_;
            for (int c = 0; c < C_; ++c) acc += r[c] * bq[c];
            ws[OFF_W + j] = acc;
        }
        if (tid == 0) {
            float acc = 0.f;
            for (int c = 0; c < C_; ++c) acc += bq[c] * bk[c];
            ws[OFF_C0] = acc;
        }
        for (int idx = tid; idx < 64 * 64; idx += 256) {
            int s = idx >> 6, t = idx & 63;
            ws[OFF_PEDOT + idx] = pe[s*3]*pe[t*3] + pe[s*3+1]*pe[t*3+1] + pe[s*3+2]*pe[t*3+2];
        }
    }
}

// ---------------- prep2: fold expert LN affine into w1/b1 ----------------
__global__ void prep2(const float* __restrict__ elng, const float* __restrict__ elnb,
                      const float* __restrict__ w1, const float* __restrict__ b1,
                      float* __restrict__ ws) {
    int b = blockIdx.x, tid = threadIdx.x;
    if (b < 256) {
        #pragma unroll
        for (int k = 0; k < 8; ++k) {
            int idx = b * 2048 + k * 256 + tid;          // < 524288
            int i = idx >> 16;
            int c = (idx >> 9) & 127;
            ws[OFF_W1P + idx] = elng[i * C_ + c] * w1[idx];
        }
    } else {
        int i = b - 256;
        for (int h = tid; h < H_; h += 256) {
            float acc = b1[i * H_ + h];
            const float* wcol = w1 + i * C_ * H_ + h;
            for (int c = 0; c < C_; ++c) acc += elnb[i * C_ + c] * wcol[c * H_];
            ws[OFF_B1P + i * H_ + h] = acc;
        }
    }
}

// ---------------- kernA: per-edge grid proj + LN + attention + out-norm ----------------
__global__ __launch_bounds__(256) void kernA(
        const float* __restrict__ message, const float* __restrict__ tg,
        const float* __restrict__ ln1g, const float* __restrict__ ln1b,
        const float* __restrict__ wvw, const float* __restrict__ bv,
        const float* __restrict__ ws_ro, float* __restrict__ nout) {
    __shared__ __align__(16) __hip_bfloat16 s_gz[64 * 128];   // g -> z -> v
    __shared__ __align__(16) __hip_bfloat16 s_mT[128 * 66];   // (stage msg) -> m^T
    __shared__ __align__(16) float          s_sc[64 * 66];    // (stage tg) -> scores/probs
    __shared__ __align__(16) float          s_st[256];        // [128..191]=mu, [192..255]=mw

    const int e = blockIdx.x, tid = threadIdx.x;

    // ---- stage: msg (fp32) overlaid on s_mT, to_grid overlaid on s_sc ----
    float* msgS = (float*)s_mT;     // 3200 floats = 12800 B <= 16896 B
    float* tgS  = s_sc;             // 1600 floats
    for (int i = tid; i < L_ * C_; i += 256) msgS[i] = message[e * L_ * C_ + i];
    for (int i = tid; i < S_ * L_; i += 256) tgS[i]  = tg[i];
    __syncthreads();

    // ---- g[s][c] = sum_l tg[s][l] * msg[l][c]  (bf16 into s_gz) ----
    {
        int s = tid >> 2, c0 = (tid & 3) * 32;
        float acc[32];
        #pragma unroll
        for (int k = 0; k < 32; ++k) acc[k] = 0.f;
        for (int l = 0; l < L_; ++l) {
            float t = tgS[s * L_ + l];
            const float* mrow = msgS + l * C_ + c0;
            #pragma unroll
            for (int k = 0; k < 32; ++k) acc[k] += t * mrow[k];
        }
        #pragma unroll
        for (int k = 0; k < 32; ++k) s_gz[s * C_ + c0 + k] = __float2bfloat16(acc[k]);
    }
    __syncthreads();

    // ---- fused LN stats + affine + transpose: m^T[c][s] ----
    {
        int wv_ = tid >> 6, lane = tid & 63;
        float g1a = ln1g[lane], g1b = ln1g[lane + 64];
        float b1a = ln1b[lane], b1b = ln1b[lane + 64];
        for (int r = 0; r < 16; ++r) {
            int s = (wv_ << 4) + r;
            float x0 = __bfloat162float(s_gz[s * C_ + lane]);
            float x1 = __bfloat162float(s_gz[s * C_ + lane + 64]);
            float sm = x0 + x1, sq = x0 * x0 + x1 * x1;
            #pragma unroll
            for (int m = 1; m < 64; m <<= 1) {
                sm += __shfl_xor(sm, m, 64);
                sq += __shfl_xor(sq, m, 64);
            }
            float mean = sm * (1.f / 128.f);
            float rstd = rsqrtf(sq * (1.f / 128.f) - mean * mean + 1e-5f);
            s_mT[lane * 66 + s]        = __float2bfloat16((x0 - mean) * rstd * g1a + b1a);
            s_mT[(lane + 64) * 66 + s] = __float2bfloat16((x1 - mean) * rstd * g1b + b1b);
        }
    }
    __syncthreads();

    // ---- z = m @ G  (z into s_gz) ----
    {
        int lam = tid & 31, sg = tid >> 5;
        int j4 = lam * 4, s0 = sg * 8;
        float acc[8][4];
        #pragma unroll
        for (int i = 0; i < 8; ++i) { acc[i][0]=0.f; acc[i][1]=0.f; acc[i][2]=0.f; acc[i][3]=0.f; }
        const float* Gbase = ws_ro + OFF_G;
        #pragma unroll 2
        for (int j = 0; j < C_; ++j) {
            float4 gr = *(const float4*)(Gbase + j * C_ + j4);
            #pragma unroll
            for (int i = 0; i < 8; ++i) {
                float mv = __bfloat162float(s_mT[j * 66 + s0 + i]);
                acc[i][0] += mv * gr.x; acc[i][1] += mv * gr.y;
                acc[i][2] += mv * gr.z; acc[i][3] += mv * gr.w;
            }
        }
        #pragma unroll
        for (int i = 0; i < 8; ++i) {
            __hip_bfloat162* dst = (__hip_bfloat162*)(s_gz + (s0 + i) * C_ + j4);
            __hip_bfloat162 p0, p1;
            p0.x = __float2bfloat16(acc[i][0]); p0.y = __float2bfloat16(acc[i][1]);
            p1.x = __float2bfloat16(acc[i][2]); p1.y = __float2bfloat16(acc[i][3]);
            dst[0] = p0; dst[1] = p1;
        }
    }
    __syncthreads();

    // ---- raw scores: sc[s][t] = sum_c z[s][c] * mT[c][t] ----
    {
        int lt = tid & 15, sg2 = tid >> 4;
        int t0 = lt * 4, s0 = sg2 * 4;
        float acc[4][4];
        #pragma unroll
        for (int i = 0; i < 4; ++i) { acc[i][0]=0.f; acc[i][1]=0.f; acc[i][2]=0.f; acc[i][3]=0.f; }
        for (int cp = 0; cp < 64; ++cp) {
            float za[4], zb[4];
            #pragma unroll
            for (int i = 0; i < 4; ++i) {
                __hip_bfloat162 zp = *(const __hip_bfloat162*)(s_gz + (s0 + i) * C_ + 2 * cp);
                za[i] = __bfloat162float(zp.x); zb[i] = __bfloat162float(zp.y);
            }
            __hip_bfloat162 ma0 = *(const __hip_bfloat162*)(s_mT + (2*cp) * 66 + t0);
            __hip_bfloat162 ma1 = *(const __hip_bfloat162*)(s_mT + (2*cp) * 66 + t0 + 2);
            __hip_bfloat162 mb0 = *(const __hip_bfloat162*)(s_mT + (2*cp+1) * 66 + t0);
            __hip_bfloat162 mb1 = *(const __hip_bfloat162*)(s_mT + (2*cp+1) * 66 + t0 + 2);
            float m0[4] = {__bfloat162float(ma0.x), __bfloat162float(ma0.y),
                           __bfloat162float(ma1.x), __bfloat162float(ma1.y)};
            float m1[4] = {__bfloat162float(mb0.x), __bfloat162float(mb0.y),
                           __bfloat162float(mb1.x), __bfloat162float(mb1.y)};
            #pragma unroll
            for (int i = 0; i < 4; ++i) {
                #pragma unroll
                for (int k = 0; k < 4; ++k)
                    acc[i][k] += za[i] * m0[k] + zb[i] * m1[k];
            }
        }
        #pragma unroll
        for (int i = 0; i < 4; ++i)
            #pragma unroll
            for (int k = 0; k < 4; ++k)
                s_sc[(s0 + i) * 66 + t0 + k] = acc[i][k];
    }
    // ---- mu[s] = m_s . u ; mw[t] = m_t . w  (wave 0 only) ----
    if (tid < 64) {
        int s = tid;
        float mu = 0.f, mw = 0.f;
        const float* u = ws_ro + OFF_U;
        const float* w = ws_ro + OFF_W;
        for (int j = 0; j < C_; ++j) {
            float mv = __bfloat162float(s_mT[j * 66 + s]);
            mu += mv * u[j]; mw += mv * w[j];
        }
        s_st[128 + s] = mu; s_st[192 + s] = mw;
    }
    __syncthreads();

    // ---- softmax over t (with scale, pedot, bias folds) ----
    {
        int wv_ = tid >> 6, lane = tid & 63;
        const float c0v = ws_ro[OFF_C0];
        const float scale = 0.08737040566610379f;   // 1/sqrt(131)
        for (int r = 0; r < 16; ++r) {
            int s = (wv_ << 4) + r;
            float x = s_sc[s * 66 + lane] + s_st[128 + s] + s_st[192 + lane]
                    + ws_ro[OFF_PEDOT + s * 64 + lane] + c0v;
            float mx = x;
            #pragma unroll
            for (int m = 1; m < 64; m <<= 1) mx = fmaxf(mx, __shfl_xor(mx, m, 64));
            float p = __expf((x - mx) * scale);
            float sm = p;
            #pragma unroll
            for (int m = 1; m < 64; m <<= 1) sm += __shfl_xor(sm, m, 64);
            s_sc[s * 66 + lane] = p / sm;
        }
    }
    __syncthreads();

    // ---- v = m @ Wv + bv  (into s_gz, overwrites dead z) ----
    {
        int lam = tid & 31, tg8 = tid >> 5;
        int c4 = lam * 4, t0v = tg8 * 8;
        float acc[8][4];
        float4 bvv = *(const float4*)(bv + c4);
        #pragma unroll
        for (int i = 0; i < 8; ++i) { acc[i][0]=bvv.x; acc[i][1]=bvv.y; acc[i][2]=bvv.z; acc[i][3]=bvv.w; }
        #pragma unroll 2
        for (int j = 0; j < C_; ++j) {
            float4 wr = *(const float4*)(wvw + j * C_ + c4);
            #pragma unroll
            for (int i = 0; i < 8; ++i) {
                float mv = __bfloat162float(s_mT[j * 66 + t0v + i]);
                acc[i][0] += mv * wr.x; acc[i][1] += mv * wr.y;
                acc[i][2] += mv * wr.z; acc[i][3] += mv * wr.w;
            }
        }
        #pragma unroll
        for (int i = 0; i < 8; ++i) {
            __hip_bfloat162* dst = (__hip_bfloat162*)(s_gz + (t0v + i) * C_ + c4);
            __hip_bfloat162 p0, p1;
            p0.x = __float2bfloat16(acc[i][0]); p0.y = __float2bfloat16(acc[i][1]);
            p1.x = __float2bfloat16(acc[i][2]); p1.y = __float2bfloat16(acc[i][3]);
            dst[0] = p0; dst[1] = p1;
        }
    }
    __syncthreads();

    // ---- out = p @ v, fused row-LN (no affine), store fp32 to ws ----
    {
        int lam = tid & 31, sg = tid >> 5;
        int c4 = lam * 4, s0 = sg * 8;
        float o[8][4];
        #pragma unroll
        for (int i = 0; i < 8; ++i) { o[i][0]=0.f; o[i][1]=0.f; o[i][2]=0.f; o[i][3]=0.f; }
        for (int t = 0; t < S_; ++t) {
            __hip_bfloat162 v0 = *(const __hip_bfloat162*)(s_gz + t * C_ + c4);
            __hip_bfloat162 v1 = *(const __hip_bfloat162*)(s_gz + t * C_ + c4 + 2);
            float vx = __bfloat162float(v0.x), vy = __bfloat162float(v0.y);
            float vz = __bfloat162float(v1.x), vw = __bfloat162float(v1.y);
            #pragma unroll
            for (int i = 0; i < 8; ++i) {
                float p = s_sc[(s0 + i) * 66 + t];
                o[i][0] += p * vx; o[i][1] += p * vy; o[i][2] += p * vz; o[i][3] += p * vw;
            }
        }
        #pragma unroll
        for (int i = 0; i < 8; ++i) {
            float sm = o[i][0] + o[i][1] + o[i][2] + o[i][3];
            float sq = o[i][0]*o[i][0] + o[i][1]*o[i][1] + o[i][2]*o[i][2] + o[i][3]*o[i][3];
            #pragma unroll
            for (int m = 1; m < 32; m <<= 1) {   // reduce across the 32 lanes sharing row s
                sm += __shfl_xor(sm, m, 64);
                sq += __shfl_xor(sq, m, 64);
            }
            float mean = sm * (1.f / 128.f);
            float rstd = rsqrtf(sq * (1.f / 128.f) - mean * mean + 1e-5f);
            float4 ov;
            ov.x = (o[i][0] - mean) * rstd; ov.y = (o[i][1] - mean) * rstd;
            ov.z = (o[i][2] - mean) * rstd; ov.w = (o[i][3] - mean) * rstd;
            *(float4*)(nout + e * 8192 + (s0 + i) * C_ + c4) = ov;
        }
    }
}

// ---------------- kernL0: l=0 scalar branch -> output row 0 ----------------
__global__ void kernL0(const float* __restrict__ message, const float* __restrict__ nlg,
                       const float* __restrict__ nlb, const float* __restrict__ fcw,
                       const float* __restrict__ fcb, float* __restrict__ out) {
    __shared__ float sn[128];
    int e = blockIdx.x, lane = threadIdx.x;   // 64 threads
    float x0 = message[e * 3200 + lane];
    float x1 = message[e * 3200 + 64 + lane];
    float sm = x0 + x1, sq = x0 * x0 + x1 * x1;
    #pragma unroll
    for (int m = 1; m < 64; m <<= 1) {
        sm += __shfl_xor(sm, m, 64);
        sq += __shfl_xor(sq, m, 64);
    }
    float mean = sm * (1.f / 128.f);
    float rstd = rsqrtf(sq * (1.f / 128.f) - mean * mean + 1e-5f);
    sn[lane]      = (x0 - mean) * rstd * nlg[lane]      + nlb[lane];
    sn[lane + 64] = (x1 - mean) * rstd * nlg[lane + 64] + nlb[lane + 64];
    __syncthreads();
    float o0 = fcb[lane], o1 = fcb[lane + 64];
    for (int j = 0; j < 128; ++j) {
        float nj = sn[j];
        o0 += nj * fcw[j * 128 + lane];
        o1 += nj * fcw[j * 128 + lane + 64];
    }
    out[e * 3200 + lane]      = o0 / (1.f + __expf(-o0));
    out[e * 3200 + 64 + lane] = o1 / (1.f + __expf(-o1));
}

// ---------------- kernC: 8 experts + gate + from_grid, write rows 1..24 ----------------
__global__ __launch_bounds__(256) void kernC(
        const float* __restrict__ nout_ro, const float* __restrict__ gate,
        const float* __restrict__ w2, const float* __restrict__ b2,
        const float* __restrict__ fg, const float* __restrict__ ws_ro,
        float* __restrict__ out) {
    __shared__ __align__(16) float sX[64 * 128];   // norm(out) then acc
    __shared__ __align__(16) float sS[64 * 128];   // silu hidden tile
    const int e = blockIdx.x, tid = threadIdx.x;

    for (int i = tid; i < 2048; i += 256)
        ((float4*)sX)[i] = ((const float4*)(nout_ro + e * 8192))[i];
    __syncthreads();

    int lam = tid & 31, sg = tid >> 5;
    int c4 = lam * 4, s0 = sg * 8;
    float acc[8][4];
    #pragma unroll
    for (int i = 0; i < 8; ++i) { acc[i][0]=0.f; acc[i][1]=0.f; acc[i][2]=0.f; acc[i][3]=0.f; }
    float gates[8];
    #pragma unroll
    for (int i = 0; i < 8; ++i) gates[i] = gate[e * 8 + i];

    const float* w1p = ws_ro + OFF_W1P;
    const float* b1p = ws_ro + OFF_B1P;

    for (int ex = 0; ex < NEXP_; ++ex) {
        for (int hb = 0; hb < 4; ++hb) {
            int h0 = hb * 128;
            // ---- P = X @ w1p + b1p, silu ----
            float p[8][4];
            float4 bb = *(const float4*)(b1p + ex * H_ + h0 + c4);
            #pragma unroll
            for (int i = 0; i < 8; ++i) { p[i][0]=bb.x; p[i][1]=bb.y; p[i][2]=bb.z; p[i][3]=bb.w; }
            const float* wbase = w1p + ex * C_ * H_ + h0 + c4;
            #pragma unroll 2
            for (int j = 0; j < C_; ++j) {
                float4 wr = *(const float4*)(wbase + j * H_);
                #pragma unroll
                for (int i = 0; i < 8; ++i) {
                    float xv = sX[(s0 + i) * C_ + j];
                    p[i][0] += xv * wr.x; p[i][1] += xv * wr.y;
                    p[i][2] += xv * wr.z; p[i][3] += xv * wr.w;
                }
            }
            #pragma unroll
            for (int i = 0; i < 8; ++i) {
                float4 sv;
                sv.x = p[i][0] / (1.f + __expf(-p[i][0]));
                sv.y = p[i][1] / (1.f + __expf(-p[i][1]));
                sv.z = p[i][2] / (1.f + __expf(-p[i][2]));
                sv.w = p[i][3] / (1.f + __expf(-p[i][3]));
                *(float4*)(sS + (s0 + i) * C_ + c4) = sv;
            }
            __syncthreads();
            // ---- t = S @ w2 ; acc += gate * t ----
            float t[8][4];
            #pragma unroll
            for (int i = 0; i < 8; ++i) { t[i][0]=0.f; t[i][1]=0.f; t[i][2]=0.f; t[i][3]=0.f; }
            const float* w2base = w2 + ex * H_ * C_ + h0 * C_ + c4;
            #pragma unroll 2
            for (int h = 0; h < 128; ++h) {
                float4 wr = *(const float4*)(w2base + h * C_);
                #pragma unroll
                for (int i = 0; i < 8; ++i) {
                    float sv = sS[(s0 + i) * C_ + h];
                    t[i][0] += sv * wr.x; t[i][1] += sv * wr.y;
                    t[i][2] += sv * wr.z; t[i][3] += sv * wr.w;
                }
            }
            float gv = gates[ex];
            #pragma unroll
            for (int i = 0; i < 8; ++i) {
                acc[i][0] += gv * t[i][0]; acc[i][1] += gv * t[i][1];
                acc[i][2] += gv * t[i][2]; acc[i][3] += gv * t[i][3];
            }
            __syncthreads();
        }
    }
    // ---- gate-weighted b2 term ----
    {
        float bt0 = 0.f, bt1 = 0.f, bt2 = 0.f, bt3 = 0.f;
        #pragma unroll
        for (int ex = 0; ex < NEXP_; ++ex) {
            float4 b2v = *(const float4*)(b2 + ex * C_ + c4);
            bt0 += gates[ex] * b2v.x; bt1 += gates[ex] * b2v.y;
            bt2 += gates[ex] * b2v.z; bt3 += gates[ex] * b2v.w;
        }
        #pragma unroll
        for (int i = 0; i < 8; ++i) {
            acc[i][0] += bt0; acc[i][1] += bt1; acc[i][2] += bt2; acc[i][3] += bt3;
        }
    }
    // ---- acc -> sX, then fro = from_grid @ acc, rows l=1..24 ----
    #pragma unroll
    for (int i = 0; i < 8; ++i) {
        float4 av; av.x = acc[i][0]; av.y = acc[i][1]; av.z = acc[i][2]; av.w = acc[i][3];
        *(float4*)(sX + (s0 + i) * C_ + c4) = av;
    }
    __syncthreads();
    for (int idx = tid; idx < 24 * C_; idx += 256) {
        int l = 1 + (idx >> 7), c = idx & 127;
        float a = 0.f;
        const float* fgr = fg + l * S_;
        for (int s = 0; s < S_; ++s) a += fgr[s] * sX[s * C_ + c];
        out[e * L_ * C_ + l * C_ + c] = a;
    }
}

extern "C" void kernel_launch(void* const* d_in, const int* in_sizes, int n_in,
                              void* d_out, int out_size, void* d_ws, size_t ws_size,
                              hipStream_t stream) {
    (void)in_sizes; (void)n_in; (void)out_size; (void)ws_size;
    const float* message = (const float*)d_in[0];
    const float* gate    = (const float*)d_in[1];
    // d_in[2] = batch (unused by reference math)
    const float* ln1g = (const float*)d_in[3];
    const float* ln1b = (const float*)d_in[4];
    const float* wq   = (const float*)d_in[5];
    const float* bq   = (const float*)d_in[6];
    const float* wk   = (const float*)d_in[7];
    const float* bk   = (const float*)d_in[8];
    const float* wv   = (const float*)d_in[9];
    const float* bv   = (const float*)d_in[10];
    const float* nlg  = (const float*)d_in[11];
    const float* nlb  = (const float*)d_in[12];
    const float* fcw  = (const float*)d_in[13];
    const float* fcb  = (const float*)d_in[14];
    const float* elng = (const float*)d_in[15];
    const float* elnb = (const float*)d_in[16];
    const float* w1   = (const float*)d_in[17];
    const float* b1   = (const float*)d_in[18];
    const float* w2   = (const float*)d_in[19];
    const float* b2   = (const float*)d_in[20];
    const float* tg   = (const float*)d_in[21];
    const float* fg   = (const float*)d_in[22];
    const float* pe   = (const float*)d_in[23];
    float* ws  = (float*)d_ws;
    float* out = (float*)d_out;

    prep1<<<dim3(65), dim3(256), 0, stream>>>(wq, bq, wk, bk, pe, ws);
    prep2<<<dim3(264), dim3(256), 0, stream>>>(elng, elnb, w1, b1, ws);
    kernA<<<dim3(E_), dim3(256), 0, stream>>>(message, tg, ln1g, ln1b, wv, bv, ws, ws + OFF_NOUT);
    kernL0<<<dim3(E_), dim3(64), 0, stream>>>(message, nlg, nlb, fcw, fcb, out);
    kernC<<<dim3(E_), dim3(256), 0, stream>>>(ws + OFF_NOUT, gate, w2, b2, fg, ws, out);
}

// Round 3
// 529.754 us; speedup vs baseline: 5.7442x; 5.7442x over previous
//
#include <hip/hip_runtime.h>
#include <hip/hip_bf16.h>

#define E_ 1024
#define L_ 25
#define S_ 64
#define C_ 128
#define H_ 512
#define NEXP_ 8

// workspace float offsets
#define OFF_G     0            // 128*128 -> ends 16384
#define OFF_U     16384        // 128
#define OFF_W     16512        // 128
#define OFF_C0    16640        // 1
#define OFF_PEDOT 16704        // 64*64 -> ends 20800
#define OFF_B1P   20800        // 8*512 fp32 -> ends 24896
#define OFF_W1S   24896        // 524288 bf16 = 262144 floats -> ends 287040
#define OFF_W2S   287040       // 524288 bf16 = 262144 floats -> ends 549184
#define OFF_NOUT  549184       // 1024*64*128 fp32 -> ends 8937792 (~35.8 MB)

typedef float floatx4 __attribute__((ext_vector_type(4)));
typedef __bf16 bf16x8 __attribute__((ext_vector_type(8)));
typedef __bf16 bf16x4 __attribute__((ext_vector_type(4)));

// ---------------- prep1: G = Wq Wk^T, u/w/c0 bias folds, pedot ----------------
__global__ void prep1(const float* __restrict__ wq, const float* __restrict__ bq,
                      const float* __restrict__ wk, const float* __restrict__ bk,
                      const float* __restrict__ pe, float* __restrict__ ws) {
    int b = blockIdx.x, tid = threadIdx.x;
    if (b < 64) {
        int a = b * 2 + (tid >> 7);
        int col = tid & 127;
        const float* ra = wq + a * C_;
        const float* rb = wk + col * C_;
        float acc = 0.f;
        for (int c = 0; c < C_; ++c) acc += ra[c] * rb[c];
        ws[OFF_G + a * C_ + col] = acc;
    } else {
        if (tid < 128) {
            float acc = 0.f; const float* r = wq + tid * C_;
            for (int c = 0; c < C_; ++c) acc += r[c] * bk[c];
            ws[OFF_U + tid] = acc;
        } else {
            int j = tid - 128;
            float acc = 0.f; const float* r = wk + j * C_;
            for (int c = 0; c < C_; ++c) acc += r[c] * bq[c];
            ws[OFF_W + j] = acc;
        }
        if (tid == 0) {
            float acc = 0.f;
            for (int c = 0; c < C_; ++c) acc += bq[c] * bk[c];
            ws[OFF_C0] = acc;
        }
        for (int idx = tid; idx < 64 * 64; idx += 256) {
            int s = idx >> 6, t = idx & 63;
            ws[OFF_PEDOT + idx] = pe[s*3]*pe[t*3] + pe[s*3+1]*pe[t*3+1] + pe[s*3+2]*pe[t*3+2];
        }
    }
}

// ---------------- prep2: b1p = elnb @ w1 + b1 (fp32) ----------------
__global__ void prep2(const float* __restrict__ elnb, const float* __restrict__ w1,
                      const float* __restrict__ b1, float* __restrict__ ws) {
    int i = blockIdx.x, tid = threadIdx.x;
    for (int h = tid; h < H_; h += 256) {
        float acc = b1[i * H_ + h];
        const float* wcol = w1 + i * C_ * H_ + h;
        for (int c = 0; c < C_; ++c) acc += elnb[i * C_ + c] * wcol[c * H_];
        ws[OFF_B1P + i * H_ + h] = acc;
    }
}

// ---------------- prepSwz: swizzle LN-folded w1 and w2 into MFMA A-frag order (bf16) ----------------
// w1s frag (ex, htg 0..32, kt 0..4): lane l, j: A[h=htg*16+(l&15)][c=kt*32+(l>>4)*8+j] = g[c]*w1[c][h]
// w2s frag (ex, ctg 0..8, ktg 0..16): lane l, j: A[c=ctg*16+(l&15)][h=ktg*32+(l>>4)*8+j] = w2[h][c]
__global__ void prepSwz(const float* __restrict__ elng, const float* __restrict__ w1,
                        const float* __restrict__ w2,
                        __hip_bfloat16* __restrict__ w1s, __hip_bfloat16* __restrict__ w2s) {
    int idx = blockIdx.x * 256 + threadIdx.x;
    if (idx < 524288) {
        int f = idx >> 9, r = idx & 511;
        int lane = r >> 3, j = r & 7;
        int kt = f & 3, htg = (f >> 2) & 31, ex = f >> 7;
        int c = kt * 32 + (lane >> 4) * 8 + j;
        int h = htg * 16 + (lane & 15);
        w1s[idx] = __float2bfloat16(elng[ex * 128 + c] * w1[ex * 65536 + c * 512 + h]);
    } else {
        int i2 = idx - 524288;
        int f = i2 >> 9, r = i2 & 511;
        int lane = r >> 3, j = r & 7;
        int ktg = f & 15, ctg = (f >> 4) & 7, ex = f >> 7;
        int h = ktg * 32 + (lane >> 4) * 8 + j;
        int c = ctg * 16 + (lane & 15);
        w2s[i2] = __float2bfloat16(w2[ex * 65536 + h * 128 + c]);
    }
}

// ---------------- kernA: per-edge grid proj + LN + attention + out-norm ----------------
__global__ __launch_bounds__(256) void kernA(
        const float* __restrict__ message, const float* __restrict__ tg,
        const float* __restrict__ ln1g, const float* __restrict__ ln1b,
        const float* __restrict__ wvw, const float* __restrict__ bv,
        const float* __restrict__ ws_ro, float* __restrict__ nout) {
    __shared__ __align__(16) __hip_bfloat16 s_gz[64 * 128];   // g -> z -> v
    __shared__ __align__(16) __hip_bfloat16 s_mT[128 * 66];   // (stage msg) -> m^T
    __shared__ __align__(16) float          s_sc[64 * 66];    // (stage tg) -> scores/probs
    __shared__ __align__(16) float          s_st[256];        // [128..191]=mu, [192..255]=mw

    const int e = blockIdx.x, tid = threadIdx.x;

    float* msgS = (float*)s_mT;
    float* tgS  = s_sc;
    for (int i = tid; i < L_ * C_; i += 256) msgS[i] = message[e * L_ * C_ + i];
    for (int i = tid; i < S_ * L_; i += 256) tgS[i]  = tg[i];
    __syncthreads();

    {
        int s = tid >> 2, c0 = (tid & 3) * 32;
        float acc[32];
        #pragma unroll
        for (int k = 0; k < 32; ++k) acc[k] = 0.f;
        for (int l = 0; l < L_; ++l) {
            float t = tgS[s * L_ + l];
            const float* mrow = msgS + l * C_ + c0;
            #pragma unroll
            for (int k = 0; k < 32; ++k) acc[k] += t * mrow[k];
        }
        #pragma unroll
        for (int k = 0; k < 32; ++k) s_gz[s * C_ + c0 + k] = __float2bfloat16(acc[k]);
    }
    __syncthreads();

    {
        int wv_ = tid >> 6, lane = tid & 63;
        float g1a = ln1g[lane], g1b = ln1g[lane + 64];
        float b1a = ln1b[lane], b1b = ln1b[lane + 64];
        for (int r = 0; r < 16; ++r) {
            int s = (wv_ << 4) + r;
            float x0 = __bfloat162float(s_gz[s * C_ + lane]);
            float x1 = __bfloat162float(s_gz[s * C_ + lane + 64]);
            float sm = x0 + x1, sq = x0 * x0 + x1 * x1;
            #pragma unroll
            for (int m = 1; m < 64; m <<= 1) {
                sm += __shfl_xor(sm, m, 64);
                sq += __shfl_xor(sq, m, 64);
            }
            float mean = sm * (1.f / 128.f);
            float rstd = rsqrtf(sq * (1.f / 128.f) - mean * mean + 1e-5f);
            s_mT[lane * 66 + s]        = __float2bfloat16((x0 - mean) * rstd * g1a + b1a);
            s_mT[(lane + 64) * 66 + s] = __float2bfloat16((x1 - mean) * rstd * g1b + b1b);
        }
    }
    __syncthreads();

    {
        int lam = tid & 31, sg = tid >> 5;
        int j4 = lam * 4, s0 = sg * 8;
        float acc[8][4];
        #pragma unroll
        for (int i = 0; i < 8; ++i) { acc[i][0]=0.f; acc[i][1]=0.f; acc[i][2]=0.f; acc[i][3]=0.f; }
        const float* Gbase = ws_ro + OFF_G;
        #pragma unroll 2
        for (int j = 0; j < C_; ++j) {
            float4 gr = *(const float4*)(Gbase + j * C_ + j4);
            #pragma unroll
            for (int i = 0; i < 8; ++i) {
                float mv = __bfloat162float(s_mT[j * 66 + s0 + i]);
                acc[i][0] += mv * gr.x; acc[i][1] += mv * gr.y;
                acc[i][2] += mv * gr.z; acc[i][3] += mv * gr.w;
            }
        }
        #pragma unroll
        for (int i = 0; i < 8; ++i) {
            __hip_bfloat162* dst = (__hip_bfloat162*)(s_gz + (s0 + i) * C_ + j4);
            __hip_bfloat162 p0, p1;
            p0.x = __float2bfloat16(acc[i][0]); p0.y = __float2bfloat16(acc[i][1]);
            p1.x = __float2bfloat16(acc[i][2]); p1.y = __float2bfloat16(acc[i][3]);
            dst[0] = p0; dst[1] = p1;
        }
    }
    __syncthreads();

    {
        int lt = tid & 15, sg2 = tid >> 4;
        int t0 = lt * 4, s0 = sg2 * 4;
        float acc[4][4];
        #pragma unroll
        for (int i = 0; i < 4; ++i) { acc[i][0]=0.f; acc[i][1]=0.f; acc[i][2]=0.f; acc[i][3]=0.f; }
        for (int cp = 0; cp < 64; ++cp) {
            float za[4], zb[4];
            #pragma unroll
            for (int i = 0; i < 4; ++i) {
                __hip_bfloat162 zp = *(const __hip_bfloat162*)(s_gz + (s0 + i) * C_ + 2 * cp);
                za[i] = __bfloat162float(zp.x); zb[i] = __bfloat162float(zp.y);
            }
            __hip_bfloat162 ma0 = *(const __hip_bfloat162*)(s_mT + (2*cp) * 66 + t0);
            __hip_bfloat162 ma1 = *(const __hip_bfloat162*)(s_mT + (2*cp) * 66 + t0 + 2);
            __hip_bfloat162 mb0 = *(const __hip_bfloat162*)(s_mT + (2*cp+1) * 66 + t0);
            __hip_bfloat162 mb1 = *(const __hip_bfloat162*)(s_mT + (2*cp+1) * 66 + t0 + 2);
            float m0[4] = {__bfloat162float(ma0.x), __bfloat162float(ma0.y),
                           __bfloat162float(ma1.x), __bfloat162float(ma1.y)};
            float m1[4] = {__bfloat162float(mb0.x), __bfloat162float(mb0.y),
                           __bfloat162float(mb1.x), __bfloat162float(mb1.y)};
            #pragma unroll
            for (int i = 0; i < 4; ++i) {
                #pragma unroll
                for (int k = 0; k < 4; ++k)
                    acc[i][k] += za[i] * m0[k] + zb[i] * m1[k];
            }
        }
        #pragma unroll
        for (int i = 0; i < 4; ++i)
            #pragma unroll
            for (int k = 0; k < 4; ++k)
                s_sc[(s0 + i) * 66 + t0 + k] = acc[i][k];
    }
    if (tid < 64) {
        int s = tid;
        float mu = 0.f, mw = 0.f;
        const float* u = ws_ro + OFF_U;
        const float* w = ws_ro + OFF_W;
        for (int j = 0; j < C_; ++j) {
            float mv = __bfloat162float(s_mT[j * 66 + s]);
            mu += mv * u[j]; mw += mv * w[j];
        }
        s_st[128 + s] = mu; s_st[192 + s] = mw;
    }
    __syncthreads();

    {
        int wv_ = tid >> 6, lane = tid & 63;
        const float c0v = ws_ro[OFF_C0];
        const float scale = 0.08737040566610379f;   // 1/sqrt(131)
        for (int r = 0; r < 16; ++r) {
            int s = (wv_ << 4) + r;
            float x = s_sc[s * 66 + lane] + s_st[128 + s] + s_st[192 + lane]
                    + ws_ro[OFF_PEDOT + s * 64 + lane] + c0v;
            float mx = x;
            #pragma unroll
            for (int m = 1; m < 64; m <<= 1) mx = fmaxf(mx, __shfl_xor(mx, m, 64));
            float p = __expf((x - mx) * scale);
            float sm = p;
            #pragma unroll
            for (int m = 1; m < 64; m <<= 1) sm += __shfl_xor(sm, m, 64);
            s_sc[s * 66 + lane] = p / sm;
        }
    }
    __syncthreads();

    {
        int lam = tid & 31, tg8 = tid >> 5;
        int c4 = lam * 4, t0v = tg8 * 8;
        float acc[8][4];
        float4 bvv = *(const float4*)(bv + c4);
        #pragma unroll
        for (int i = 0; i < 8; ++i) { acc[i][0]=bvv.x; acc[i][1]=bvv.y; acc[i][2]=bvv.z; acc[i][3]=bvv.w; }
        #pragma unroll 2
        for (int j = 0; j < C_; ++j) {
            float4 wr = *(const float4*)(wvw + j * C_ + c4);
            #pragma unroll
            for (int i = 0; i < 8; ++i) {
                float mv = __bfloat162float(s_mT[j * 66 + t0v + i]);
                acc[i][0] += mv * wr.x; acc[i][1] += mv * wr.y;
                acc[i][2] += mv * wr.z; acc[i][3] += mv * wr.w;
            }
        }
        #pragma unroll
        for (int i = 0; i < 8; ++i) {
            __hip_bfloat162* dst = (__hip_bfloat162*)(s_gz + (t0v + i) * C_ + c4);
            __hip_bfloat162 p0, p1;
            p0.x = __float2bfloat16(acc[i][0]); p0.y = __float2bfloat16(acc[i][1]);
            p1.x = __float2bfloat16(acc[i][2]); p1.y = __float2bfloat16(acc[i][3]);
            dst[0] = p0; dst[1] = p1;
        }
    }
    __syncthreads();

    {
        int lam = tid & 31, sg = tid >> 5;
        int c4 = lam * 4, s0 = sg * 8;
        float o[8][4];
        #pragma unroll
        for (int i = 0; i < 8; ++i) { o[i][0]=0.f; o[i][1]=0.f; o[i][2]=0.f; o[i][3]=0.f; }
        for (int t = 0; t < S_; ++t) {
            __hip_bfloat162 v0 = *(const __hip_bfloat162*)(s_gz + t * C_ + c4);
            __hip_bfloat162 v1 = *(const __hip_bfloat162*)(s_gz + t * C_ + c4 + 2);
            float vx = __bfloat162float(v0.x), vy = __bfloat162float(v0.y);
            float vz = __bfloat162float(v1.x), vw = __bfloat162float(v1.y);
            #pragma unroll
            for (int i = 0; i < 8; ++i) {
                float p = s_sc[(s0 + i) * 66 + t];
                o[i][0] += p * vx; o[i][1] += p * vy; o[i][2] += p * vz; o[i][3] += p * vw;
            }
        }
        #pragma unroll
        for (int i = 0; i < 8; ++i) {
            float sm = o[i][0] + o[i][1] + o[i][2] + o[i][3];
            float sq = o[i][0]*o[i][0] + o[i][1]*o[i][1] + o[i][2]*o[i][2] + o[i][3]*o[i][3];
            #pragma unroll
            for (int m = 1; m < 32; m <<= 1) {
                sm += __shfl_xor(sm, m, 64);
                sq += __shfl_xor(sq, m, 64);
            }
            float mean = sm * (1.f / 128.f);
            float rstd = rsqrtf(sq * (1.f / 128.f) - mean * mean + 1e-5f);
            float4 ov;
            ov.x = (o[i][0] - mean) * rstd; ov.y = (o[i][1] - mean) * rstd;
            ov.z = (o[i][2] - mean) * rstd; ov.w = (o[i][3] - mean) * rstd;
            *(float4*)(nout + (size_t)e * 8192 + (s0 + i) * C_ + c4) = ov;
        }
    }
}

// ---------------- kernL0: l=0 scalar branch -> output row 0 ----------------
__global__ void kernL0(const float* __restrict__ message, const float* __restrict__ nlg,
                       const float* __restrict__ nlb, const float* __restrict__ fcw,
                       const float* __restrict__ fcb, float* __restrict__ out) {
    __shared__ float sn[128];
    int e = blockIdx.x, lane = threadIdx.x;   // 64 threads
    float x0 = message[e * 3200 + lane];
    float x1 = message[e * 3200 + 64 + lane];
    float sm = x0 + x1, sq = x0 * x0 + x1 * x1;
    #pragma unroll
    for (int m = 1; m < 64; m <<= 1) {
        sm += __shfl_xor(sm, m, 64);
        sq += __shfl_xor(sq, m, 64);
    }
    float mean = sm * (1.f / 128.f);
    float rstd = rsqrtf(sq * (1.f / 128.f) - mean * mean + 1e-5f);
    sn[lane]      = (x0 - mean) * rstd * nlg[lane]      + nlb[lane];
    sn[lane + 64] = (x1 - mean) * rstd * nlg[lane + 64] + nlb[lane + 64];
    __syncthreads();
    float o0 = fcb[lane], o1 = fcb[lane + 64];
    for (int j = 0; j < 128; ++j) {
        float nj = sn[j];
        o0 += nj * fcw[j * 128 + lane];
        o1 += nj * fcw[j * 128 + lane + 64];
    }
    out[e * 3200 + lane]      = o0 / (1.f + __expf(-o0));
    out[e * 3200 + 64 + lane] = o1 / (1.f + __expf(-o1));
}

// ---------------- kernC: MFMA expert MLPs (2 edges/block) + from_grid ----------------
// matmul1: P^T = (g.w1)^T @ X^T  (M=h, N=s, K=c);  matmul2: T^T = w2^T @ S^T (M=c, N=s, K=h)
// C/D layout (verified): col=lane&15 (N), row=quad*4+reg (M). A-frag: A[m=lane&15][k=quad*8+j].
__global__ __launch_bounds__(256, 2) void kernC(
        const float* __restrict__ nout_ro, const float* __restrict__ gate,
        const __hip_bfloat16* __restrict__ w1s, const __hip_bfloat16* __restrict__ w2s,
        const float* __restrict__ b1p, const float* __restrict__ b2,
        const float* __restrict__ fg, float* __restrict__ out) {

    __shared__ __align__(16) char smem[128 * 272 + 64 * 272];   // sX 34816 + sS 17408
    __shared__ float sGB2[2][128];
    char* sXb = smem;                 // X[n=128][c=128] bf16, row stride 272 B
    char* sSb = smem + 128 * 272;     // S[n=64][h=128] bf16, row stride 272 B
    float* sAcc = (float*)smem;       // epilogue overlay: acc[s=64][c], row stride 132 fl

    const int e0 = blockIdx.x * 2;
    const int tid = threadIdx.x;
    const int w = tid >> 6, lane = tid & 63;
    const int quad = lane >> 4, col = lane & 15;
    const int htB = (w >> 1) * 4;      // M-tile base (matmul1: h, matmul2: c)
    const int stB = (w & 1) * 2;       // N-tile base (s)

    // ---- stage X (fp32 -> bf16): rows n = e_local*64 + s ----
    for (int i = tid; i < 2048; i += 256) {
        const float* src = nout_ro + (size_t)e0 * 8192 + i * 8;
        float4 f0 = *(const float4*)src;
        float4 f1 = *(const float4*)(src + 4);
        bf16x8 v;
        v[0]=(__bf16)f0.x; v[1]=(__bf16)f0.y; v[2]=(__bf16)f0.z; v[3]=(__bf16)f0.w;
        v[4]=(__bf16)f1.x; v[5]=(__bf16)f1.y; v[6]=(__bf16)f1.z; v[7]=(__bf16)f1.w;
        int n = i >> 4, k0 = (i & 15) * 8;
        *(bf16x8*)(sXb + n * 272 + k0 * 2) = v;
    }
    {   // gate-weighted b2 per edge
        int e_l = tid >> 7, c = tid & 127;
        float s = 0.f;
        #pragma unroll
        for (int ex = 0; ex < 8; ++ex) s += gate[(e0 + e_l) * 8 + ex] * b2[ex * 128 + c];
        sGB2[e_l][c] = s;
    }
    __syncthreads();

    floatx4 accT[2][4][2];   // [edge][ct][st]
    #pragma unroll
    for (int e = 0; e < 2; ++e)
        #pragma unroll
        for (int m = 0; m < 4; ++m)
            #pragma unroll
            for (int n2 = 0; n2 < 2; ++n2) accT[e][m][n2] = (floatx4)0.f;

    for (int ex = 0; ex < NEXP_; ++ex) {
        for (int hb = 0; hb < 4; ++hb) {
            for (int ph = 0; ph < 2; ++ph) {       // edge phase
                const float gv = gate[(e0 + ph) * 8 + ex];
                // ---- matmul1: P^T[h 128][s 64] ----
                floatx4 accP[4][2];
                #pragma unroll
                for (int mt = 0; mt < 4; ++mt) {
                    int h = hb * 128 + (htB + mt) * 16 + quad * 4;
                    float4 bv = *(const float4*)(b1p + ex * 512 + h);
                    #pragma unroll
                    for (int nt = 0; nt < 2; ++nt) {
                        accP[mt][nt][0] = bv.x; accP[mt][nt][1] = bv.y;
                        accP[mt][nt][2] = bv.z; accP[mt][nt][3] = bv.w;
                    }
                }
                #pragma unroll
                for (int kt = 0; kt < 4; ++kt) {
                    bf16x8 a[4], b[2];
                    #pragma unroll
                    for (int mt = 0; mt < 4; ++mt)
                        a[mt] = *(const bf16x8*)(w1s + (size_t)((ex*32 + hb*8 + htB + mt)*4 + kt)*512 + lane*8);
                    #pragma unroll
                    for (int nt = 0; nt < 2; ++nt) {
                        int n = ph * 64 + (stB + nt) * 16 + col;
                        b[nt] = *(const bf16x8*)(sXb + n * 272 + kt * 64 + quad * 16);
                    }
                    #pragma unroll
                    for (int mt = 0; mt < 4; ++mt)
                        #pragma unroll
                        for (int nt = 0; nt < 2; ++nt)
                            accP[mt][nt] = __builtin_amdgcn_mfma_f32_16x16x32_bf16(a[mt], b[nt], accP[mt][nt], 0, 0, 0);
                }
                // ---- silu * gate -> S (packed b64 writes: 4 consecutive h) ----
                #pragma unroll
                for (int mt = 0; mt < 4; ++mt) {
                    int hl = (htB + mt) * 16 + quad * 4;
                    #pragma unroll
                    for (int nt = 0; nt < 2; ++nt) {
                        int nl = (stB + nt) * 16 + col;
                        bf16x4 sv;
                        #pragma unroll
                        for (int r = 0; r < 4; ++r) {
                            float p = accP[mt][nt][r];
                            sv[r] = (__bf16)(gv * p / (1.f + __expf(-p)));
                        }
                        *(bf16x4*)(sSb + nl * 272 + hl * 2) = sv;
                    }
                }
                __syncthreads();
                // ---- matmul2: accT[ph] += w2^T @ S^T ----
                #pragma unroll
                for (int kt = 0; kt < 4; ++kt) {
                    bf16x8 a[4], b[2];
                    #pragma unroll
                    for (int mt = 0; mt < 4; ++mt)
                        a[mt] = *(const bf16x8*)(w2s + (size_t)((ex*8 + htB + mt)*16 + hb*4 + kt)*512 + lane*8);
                    #pragma unroll
                    for (int nt = 0; nt < 2; ++nt) {
                        int nl = (stB + nt) * 16 + col;
                        b[nt] = *(const bf16x8*)(sSb + nl * 272 + kt * 64 + quad * 16);
                    }
                    #pragma unroll
                    for (int mt = 0; mt < 4; ++mt)
                        #pragma unroll
                        for (int nt = 0; nt < 2; ++nt)
                            accT[ph][mt][nt] = __builtin_amdgcn_mfma_f32_16x16x32_bf16(a[mt], b[nt], accT[ph][mt][nt], 0, 0, 0);
                }
                __syncthreads();
            }
        }
    }

    // ---- epilogue: per edge, acc -> sAcc, then out[l][c] = sum_s fg[l][s] * acc[s][c] ----
    for (int e = 0; e < 2; ++e) {
        #pragma unroll
        for (int mt = 0; mt < 4; ++mt) {
            int c = (htB + mt) * 16 + quad * 4;
            float4 gb = *(const float4*)(&sGB2[e][c]);
            #pragma unroll
            for (int nt = 0; nt < 2; ++nt) {
                int nl = (stB + nt) * 16 + col;
                float4 v;
                v.x = accT[e][mt][nt][0] + gb.x;
                v.y = accT[e][mt][nt][1] + gb.y;
                v.z = accT[e][mt][nt][2] + gb.z;
                v.w = accT[e][mt][nt][3] + gb.w;
                *(float4*)(sAcc + nl * 132 + c) = v;
            }
        }
        __syncthreads();
        for (int idx = tid; idx < 768; idx += 256) {
            int l = 1 + (idx >> 5);
            int c4 = (idx & 31) * 4;
            float4 a4 = {0.f, 0.f, 0.f, 0.f};
            const float* fgr = fg + l * 64;
            for (int s = 0; s < 64; ++s) {
                float f = fgr[s];
                const float* row = sAcc + s * 132 + c4;
                a4.x += f * row[0]; a4.y += f * row[1]; a4.z += f * row[2]; a4.w += f * row[3];
            }
            *(float4*)(out + (size_t)(e0 + e) * 3200 + l * 128 + c4) = a4;
        }
        __syncthreads();
    }
}

extern "C" void kernel_launch(void* const* d_in, const int* in_sizes, int n_in,
                              void* d_out, int out_size, void* d_ws, size_t ws_size,
                              hipStream_t stream) {
    (void)in_sizes; (void)n_in; (void)out_size; (void)ws_size;
    const float* message = (const float*)d_in[0];
    const float* gate    = (const float*)d_in[1];
    // d_in[2] = batch (unused by reference math)
    const float* ln1g = (const float*)d_in[3];
    const float* ln1b = (const float*)d_in[4];
    const float* wq   = (const float*)d_in[5];
    const float* bq   = (const float*)d_in[6];
    const float* wk   = (const float*)d_in[7];
    const float* bk   = (const float*)d_in[8];
    const float* wv   = (const float*)d_in[9];
    const float* bv   = (const float*)d_in[10];
    const float* nlg  = (const float*)d_in[11];
    const float* nlb  = (const float*)d_in[12];
    const float* fcw  = (const float*)d_in[13];
    const float* fcb  = (const float*)d_in[14];
    const float* elng = (const float*)d_in[15];
    const float* elnb = (const float*)d_in[16];
    const float* w1   = (const float*)d_in[17];
    const float* b1   = (const float*)d_in[18];
    const float* w2   = (const float*)d_in[19];
    const float* b2   = (const float*)d_in[20];
    const float* tg   = (const float*)d_in[21];
    const float* fg   = (const float*)d_in[22];
    const float* pe   = (const float*)d_in[23];
    float* ws  = (float*)d_ws;
    float* out = (float*)d_out;
    __hip_bfloat16* w1s = (__hip_bfloat16*)(ws + OFF_W1S);
    __hip_bfloat16* w2s = (__hip_bfloat16*)(ws + OFF_W2S);

    prep1<<<dim3(65), dim3(256), 0, stream>>>(wq, bq, wk, bk, pe, ws);
    prep2<<<dim3(8), dim3(256), 0, stream>>>(elnb, w1, b1, ws);
    prepSwz<<<dim3(4096), dim3(256), 0, stream>>>(elng, w1, w2, w1s, w2s);
    kernA<<<dim3(E_), dim3(256), 0, stream>>>(message, tg, ln1g, ln1b, wv, bv, ws, ws + OFF_NOUT);
    kernL0<<<dim3(E_), dim3(64), 0, stream>>>(message, nlg, nlb, fcw, fcb, out);
    kernC<<<dim3(E_ / 2), dim3(256), 0, stream>>>(ws + OFF_NOUT, gate,
                                                  w1s, w2s, ws + OFF_B1P, b2, fg, out);
}

// Round 5
// 448.707 us; speedup vs baseline: 6.7817x; 1.1806x over previous
//
#include <hip/hip_runtime.h>
#include <hip/hip_bf16.h>

#define E_ 1024
#define L_ 25
#define S_ 64
#define C_ 128
#define H_ 512
#define NEXP_ 8

// workspace float offsets
#define OFF_W     0         // 128 (wk @ bq fold, for mw[t])
#define OFF_PEDOT 128       // 64*64 -> 4224
#define OFF_B1P   4224      // 8*512 -> 8320
#define OFF_GTF   8320      // 16384 bf16 (G^T frags, 32 frags) = 8192 fl -> 16512
#define OFF_WVTF  16512     // 16384 bf16 (Wv^T frags) -> 24704
#define OFF_G     24704     // 128*128 fp32 -> 41088
#define OFF_W1S   41088     // 524288 bf16 = 262144 fl -> 303232
#define OFF_W2S   303232    // 524288 bf16 -> 565376
#define OFF_GG    565376    // 1024*64*128 bf16 = 4194304 fl -> 4759680
#define OFF_NOUT  4759680   // 1024*64*128 bf16 -> 8953984 (~35.8 MB)

typedef float floatx4 __attribute__((ext_vector_type(4)));
typedef __bf16 bf16x8 __attribute__((ext_vector_type(8)));
typedef __bf16 bf16x4 __attribute__((ext_vector_type(4)));

// ---------------- prep1: G = Wq Wk^T, w fold, pedot ----------------
__global__ void prep1(const float* __restrict__ wq, const float* __restrict__ bq,
                      const float* __restrict__ wk, const float* __restrict__ bk,
                      const float* __restrict__ pe, float* __restrict__ ws) {
    int b = blockIdx.x, tid = threadIdx.x;
    (void)bk;
    if (b < 64) {
        int a = b * 2 + (tid >> 7);
        int col = tid & 127;
        const float* ra = wq + a * C_;
        const float* rb = wk + col * C_;
        float acc = 0.f;
        for (int c = 0; c < C_; ++c) acc += ra[c] * rb[c];
        ws[OFF_G + a * C_ + col] = acc;
    } else {
        if (tid < 128) {   // w[j] = wk_row_j . bq   (mw[t] = m_t . w)
            float acc = 0.f; const float* r = wk + tid * C_;
            for (int c = 0; c < C_; ++c) acc += r[c] * bq[c];
            ws[OFF_W + tid] = acc;
        }
        for (int idx = tid; idx < 64 * 64; idx += 256) {
            int s = idx >> 6, t = idx & 63;
            ws[OFF_PEDOT + idx] = pe[s*3]*pe[t*3] + pe[s*3+1]*pe[t*3+1] + pe[s*3+2]*pe[t*3+2];
        }
    }
}

// ---------------- prep2: b1p = elnb @ w1 + b1 (fp32) ----------------
__global__ void prep2(const float* __restrict__ elnb, const float* __restrict__ w1,
                      const float* __restrict__ b1, float* __restrict__ ws) {
    int i = blockIdx.x, tid = threadIdx.x;
    for (int h = tid; h < H_; h += 256) {
        float acc = b1[i * H_ + h];
        const float* wcol = w1 + i * C_ * H_ + h;
        for (int c = 0; c < C_; ++c) acc += elnb[i * C_ + c] * wcol[c * H_];
        ws[OFF_B1P + i * H_ + h] = acc;
    }
}

// ---------------- prepSwz: LN-folded w1 / w2 -> MFMA A-frag order (bf16) ----------------
__global__ void prepSwz(const float* __restrict__ elng, const float* __restrict__ w1,
                        const float* __restrict__ w2,
                        __hip_bfloat16* __restrict__ w1s, __hip_bfloat16* __restrict__ w2s) {
    int idx = blockIdx.x * 256 + threadIdx.x;
    if (idx < 524288) {
        int f = idx >> 9, r = idx & 511;
        int lane = r >> 3, j = r & 7;
        int kt = f & 3, htg = (f >> 2) & 31, ex = f >> 7;
        int c = kt * 32 + (lane >> 4) * 8 + j;
        int h = htg * 16 + (lane & 15);
        w1s[idx] = __float2bfloat16(elng[ex * 128 + c] * w1[ex * 65536 + c * 512 + h]);
    } else {
        int i2 = idx - 524288;
        int f = i2 >> 9, r = i2 & 511;
        int lane = r >> 3, j = r & 7;
        int ktg = f & 15, ctg = (f >> 4) & 7, ex = f >> 7;
        int h = ktg * 32 + (lane >> 4) * 8 + j;
        int c = ctg * 16 + (lane & 15);
        w2s[i2] = __float2bfloat16(w2[ex * 65536 + h * 128 + c]);
    }
}

// ---------------- prepSwzA: G and Wv^T -> MFMA B-frag order (bf16), 32 frags each ----------------
// B-frag convention (proven in kernC): Brow[n][k], frag f = Nt*4+kt holds 512 bf16,
// element lane*8+j = Brow[Nt*16+(lane&15)][kt*32+(lane>>4)*8+j]
__global__ void prepSwzA(const float* __restrict__ ws, const float* __restrict__ wv,
                         __hip_bfloat16* __restrict__ gtf, __hip_bfloat16* __restrict__ wvtf) {
    int idx = blockIdx.x * 256 + threadIdx.x;   // < 32768
    int i2 = idx & 16383;
    int f = i2 >> 9, r = i2 & 511;    // f 0..31
    int lane = r >> 3, j = r & 7;
    int kt = f & 3, Nt = f >> 2;      // Nt 0..7
    int k = kt * 32 + (lane >> 4) * 8 + j;     // K index (c for G, j_in for WvT)
    int n = Nt * 16 + (lane & 15);             // N index (j_out for G, c for WvT)
    if (idx < 16384) {
        gtf[i2] = __float2bfloat16(ws[OFF_G + k * 128 + n]);   // Brow[j][c] = G[c][j]
    } else {
        wvtf[i2] = __float2bfloat16(wv[k * 128 + n]);          // Brow[c][j] = wv[j][c]
    }
}

// ---------------- kernG: g = to_grid @ message, bf16 out ----------------
__global__ __launch_bounds__(256) void kernG(const float* __restrict__ message,
                                             const float* __restrict__ tg,
                                             __hip_bfloat16* __restrict__ gg) {
    __shared__ float sM[3200];
    __shared__ float sT[1600];
    const int e = blockIdx.x, tid = threadIdx.x;
    for (int i = tid; i < 3200; i += 256) sM[i] = message[e * 3200 + i];
    for (int i = tid; i < 1600; i += 256) sT[i] = tg[i];
    __syncthreads();
    int s = tid >> 2, c0 = (tid & 3) * 32;
    float acc[32];
    #pragma unroll
    for (int k = 0; k < 32; ++k) acc[k] = 0.f;
    for (int l = 0; l < L_; ++l) {
        float t = sT[s * L_ + l];
        const float* row = sM + l * 128 + c0;
        #pragma unroll
        for (int k = 0; k < 32; ++k) acc[k] += t * row[k];
    }
    __hip_bfloat16* dst = gg + (size_t)e * 8192 + s * 128 + c0;
    #pragma unroll
    for (int q = 0; q < 4; ++q) {
        bf16x8 v;
        #pragma unroll
        for (int k = 0; k < 8; ++k) v[k] = (__bf16)acc[q * 8 + k];
        *(bf16x8*)(dst + q * 8) = v;
    }
}

// ---------------- kernA: MFMA attention per edge ----------------
// Conventions (verified via passing kernC): D[m][n] = sum_k A[m][k]*Brow[n][k]
//   A-frag: row lane&15, bytes kt*64 + quad*16 of a row-major K-contiguous row
//   B-frag: same pattern on Brow
//   C/D:    n = Ntbase + col, m = Mtbase + quad*4 + reg
__global__ __launch_bounds__(256) void kernA(
        const __hip_bfloat16* __restrict__ gg, const float* __restrict__ ln1g,
        const float* __restrict__ ln1b, const float* __restrict__ bv,
        const float* __restrict__ ws_ro,
        const __hip_bfloat16* __restrict__ gtf, const __hip_bfloat16* __restrict__ wvtf,
        __hip_bfloat16* __restrict__ nout) {
    __shared__ __align__(16) char sA[64 * 272];    // m rows [s][c]
    __shared__ __align__(16) char sB[64 * 272];    // z rows -> p rows -> out rows
    __shared__ __align__(16) char sC[128 * 144];   // sc fp32 [64][68] -> vT rows [c][t]
    __shared__ __align__(16) float sStP[512];      // LN partials [s][wave][2]
    __shared__ __align__(16) float sSt2[128];      // [s][mean,rstd]
    __shared__ float sMw[64];

    const int e = blockIdx.x, tid = threadIdx.x;
    const int w = tid >> 6, lane = tid & 63, quad = lane >> 4, col = lane & 15;

    // ---- 1. LN(g) -> m rows (bf16) ----
    {
        float g1a = ln1g[lane], g1b = ln1g[lane + 64];
        float b1a = ln1b[lane], b1b = ln1b[lane + 64];
        const __hip_bfloat16* ge = gg + (size_t)e * 8192;
        for (int r = 0; r < 16; ++r) {
            int s = w * 16 + r;
            float x0 = __bfloat162float(ge[s * 128 + lane]);
            float x1 = __bfloat162float(ge[s * 128 + 64 + lane]);
            float sm = x0 + x1, sq = x0 * x0 + x1 * x1;
            #pragma unroll
            for (int m = 1; m < 64; m <<= 1) {
                sm += __shfl_xor(sm, m, 64);
                sq += __shfl_xor(sq, m, 64);
            }
            float mean = sm * (1.f / 128.f);
            float rstd = rsqrtf(sq * (1.f / 128.f) - mean * mean + 1e-5f);
            __hip_bfloat16* mr = (__hip_bfloat16*)(sA + s * 272);
            mr[lane]      = __float2bfloat16((x0 - mean) * rstd * g1a + b1a);
            mr[lane + 64] = __float2bfloat16((x1 - mean) * rstd * g1b + b1b);
        }
    }
    __syncthreads();   // S1

    // ---- 2. mw[t] = m_t . w ----
    {
        int t = tid >> 2, part = tid & 3;
        const __hip_bfloat16* mr = (const __hip_bfloat16*)(sA + t * 272) + part * 32;
        const float* wv_ = ws_ro + OFF_W + part * 32;
        float acc = 0.f;
        #pragma unroll
        for (int k = 0; k < 32; ++k) acc += __bfloat162float(mr[k]) * wv_[k];
        acc += __shfl_xor(acc, 1, 64);
        acc += __shfl_xor(acc, 2, 64);
        if (part == 0) sMw[t] = acc;
    }

    // ---- 3. z = m @ G (B-frags) ----
    {
        floatx4 accZ[4][2];
        #pragma unroll
        for (int mt = 0; mt < 4; ++mt) { accZ[mt][0] = (floatx4)0.f; accZ[mt][1] = (floatx4)0.f; }
        #pragma unroll
        for (int kt = 0; kt < 4; ++kt) {
            bf16x8 a[4], b[2];
            #pragma unroll
            for (int mt = 0; mt < 4; ++mt)
                a[mt] = *(const bf16x8*)(sA + (mt * 16 + col) * 272 + kt * 64 + quad * 16);
            #pragma unroll
            for (int nt = 0; nt < 2; ++nt)
                b[nt] = *(const bf16x8*)(gtf + ((2 * w + nt) * 4 + kt) * 512 + lane * 8);
            #pragma unroll
            for (int mt = 0; mt < 4; ++mt)
                #pragma unroll
                for (int nt = 0; nt < 2; ++nt)
                    accZ[mt][nt] = __builtin_amdgcn_mfma_f32_16x16x32_bf16(a[mt], b[nt], accZ[mt][nt], 0, 0, 0);
        }
        #pragma unroll
        for (int mt = 0; mt < 4; ++mt)
            #pragma unroll
            for (int nt = 0; nt < 2; ++nt) {
                int j = (2 * w + nt) * 16 + col;
                #pragma unroll
                for (int reg = 0; reg < 4; ++reg)
                    ((__hip_bfloat16*)(sB + (mt * 16 + quad * 4 + reg) * 272))[j] =
                        __float2bfloat16(accZ[mt][nt][reg]);
            }
    }
    __syncthreads();   // S2

    // ---- 4. sc = z @ m^T (N-strip per wave) ----
    {
        floatx4 accS[4];
        #pragma unroll
        for (int mt = 0; mt < 4; ++mt) accS[mt] = (floatx4)0.f;
        #pragma unroll
        for (int kt = 0; kt < 4; ++kt) {
            bf16x8 a[4];
            #pragma unroll
            for (int mt = 0; mt < 4; ++mt)
                a[mt] = *(const bf16x8*)(sB + (mt * 16 + col) * 272 + kt * 64 + quad * 16);
            bf16x8 b = *(const bf16x8*)(sA + (w * 16 + col) * 272 + kt * 64 + quad * 16);
            #pragma unroll
            for (int mt = 0; mt < 4; ++mt)
                accS[mt] = __builtin_amdgcn_mfma_f32_16x16x32_bf16(a[mt], b, accS[mt], 0, 0, 0);
        }
        float* sc = (float*)sC;
        #pragma unroll
        for (int mt = 0; mt < 4; ++mt)
            #pragma unroll
            for (int reg = 0; reg < 4; ++reg)
                sc[(mt * 16 + quad * 4 + reg) * 68 + w * 16 + col] = accS[mt][reg];
    }
    __syncthreads();   // S3

    // ---- 5. softmax rows (mu[s], bq.bk cancel; keep mw[t], pedot) -> p rows bf16 ----
    {
        const float scale = 0.08737040566610379f;   // 1/sqrt(131)
        const float* sc = (const float*)sC;
        const float* pd = ws_ro + OFF_PEDOT;
        for (int r = 0; r < 16; ++r) {
            int s = w * 16 + r;
            float x = sc[s * 68 + lane] + sMw[lane] + pd[s * 64 + lane];
            float mx = x;
            #pragma unroll
            for (int m = 1; m < 64; m <<= 1) mx = fmaxf(mx, __shfl_xor(mx, m, 64));
            float p = __expf((x - mx) * scale);
            float sm = p;
            #pragma unroll
            for (int m = 1; m < 64; m <<= 1) sm += __shfl_xor(sm, m, 64);
            ((__hip_bfloat16*)(sB + s * 272))[lane] = __float2bfloat16(p / sm);
        }
    }
    __syncthreads();   // S4 (sc dead, p ready)

    // ---- 6. v = m @ Wv^T-frags + bv -> vT rows [c][t] ----
    {
        floatx4 accV[4][2];
        #pragma unroll
        for (int mt = 0; mt < 4; ++mt) { accV[mt][0] = (floatx4)0.f; accV[mt][1] = (floatx4)0.f; }
        #pragma unroll
        for (int kt = 0; kt < 4; ++kt) {
            bf16x8 a[4], b[2];
            #pragma unroll
            for (int mt = 0; mt < 4; ++mt)
                a[mt] = *(const bf16x8*)(sA + (mt * 16 + col) * 272 + kt * 64 + quad * 16);
            #pragma unroll
            for (int nt = 0; nt < 2; ++nt)
                b[nt] = *(const bf16x8*)(wvtf + ((2 * w + nt) * 4 + kt) * 512 + lane * 8);
            #pragma unroll
            for (int mt = 0; mt < 4; ++mt)
                #pragma unroll
                for (int nt = 0; nt < 2; ++nt)
                    accV[mt][nt] = __builtin_amdgcn_mfma_f32_16x16x32_bf16(a[mt], b[nt], accV[mt][nt], 0, 0, 0);
        }
        #pragma unroll
        for (int nt = 0; nt < 2; ++nt) {
            int c = (2 * w + nt) * 16 + col;
            float bvv = bv[c];
            #pragma unroll
            for (int mt = 0; mt < 4; ++mt) {
                bf16x4 pk;
                #pragma unroll
                for (int reg = 0; reg < 4; ++reg)
                    pk[reg] = (__bf16)(accV[mt][nt][reg] + bvv);
                *(bf16x4*)(sC + c * 144 + (mt * 16 + quad * 4) * 2) = pk;
            }
        }
    }
    __syncthreads();   // S5

    // ---- 7. out = p @ vT ----
    floatx4 accO[4][2];
    #pragma unroll
    for (int mt = 0; mt < 4; ++mt) { accO[mt][0] = (floatx4)0.f; accO[mt][1] = (floatx4)0.f; }
    #pragma unroll
    for (int kt = 0; kt < 2; ++kt) {
        bf16x8 a[4], b[2];
        #pragma unroll
        for (int mt = 0; mt < 4; ++mt)
            a[mt] = *(const bf16x8*)(sB + (mt * 16 + col) * 272 + kt * 64 + quad * 16);
        #pragma unroll
        for (int nt = 0; nt < 2; ++nt)
            b[nt] = *(const bf16x8*)(sC + ((2 * w + nt) * 16 + col) * 144 + kt * 64 + quad * 16);
        #pragma unroll
        for (int mt = 0; mt < 4; ++mt)
            #pragma unroll
            for (int nt = 0; nt < 2; ++nt)
                accO[mt][nt] = __builtin_amdgcn_mfma_f32_16x16x32_bf16(a[mt], b[nt], accO[mt][nt], 0, 0, 0);
    }

    // ---- 8. LN partials per row ----
    #pragma unroll
    for (int mt = 0; mt < 4; ++mt)
        #pragma unroll
        for (int reg = 0; reg < 4; ++reg) {
            float v0 = accO[mt][0][reg], v1 = accO[mt][1][reg];
            float sm = v0 + v1, sq = v0 * v0 + v1 * v1;
            #pragma unroll
            for (int m = 1; m < 16; m <<= 1) {
                sm += __shfl_xor(sm, m, 64);
                sq += __shfl_xor(sq, m, 64);
            }
            if (col == 0) {
                int s = mt * 16 + quad * 4 + reg;
                sStP[(s * 4 + w) * 2]     = sm;
                sStP[(s * 4 + w) * 2 + 1] = sq;
            }
        }
    __syncthreads();   // S6
    if (tid < 64) {
        float sm = 0.f, sq = 0.f;
        #pragma unroll
        for (int k = 0; k < 4; ++k) {
            sm += sStP[(tid * 4 + k) * 2];
            sq += sStP[(tid * 4 + k) * 2 + 1];
        }
        float mean = sm * (1.f / 128.f);
        float rstd = rsqrtf(sq * (1.f / 128.f) - mean * mean + 1e-5f);
        sSt2[tid * 2] = mean; sSt2[tid * 2 + 1] = rstd;
    }
    __syncthreads();   // S7

    // ---- 9. normalize -> out rows bf16 (sB; p dead) ----
    #pragma unroll
    for (int mt = 0; mt < 4; ++mt)
        #pragma unroll
        for (int reg = 0; reg < 4; ++reg) {
            int s = mt * 16 + quad * 4 + reg;
            float mean = sSt2[s * 2], rstd = sSt2[s * 2 + 1];
            #pragma unroll
            for (int nt = 0; nt < 2; ++nt) {
                int c = (2 * w + nt) * 16 + col;
                ((__hip_bfloat16*)(sB + s * 272))[c] =
                    __float2bfloat16((accO[mt][nt][reg] - mean) * rstd);
            }
        }
    __syncthreads();   // S8

    // ---- 10. coalesced store nout bf16 ----
    for (int i = tid; i < 1024; i += 256) {
        int row = i >> 4, c16 = i & 15;
        bf16x8 v = *(const bf16x8*)(sB + row * 272 + c16 * 16);
        *(bf16x8*)(nout + (size_t)e * 8192 + row * 128 + c16 * 8) = v;
    }
}

// ---------------- kernL0: l=0 scalar branch -> output row 0 ----------------
__global__ void kernL0(const float* __restrict__ message, const float* __restrict__ nlg,
                       const float* __restrict__ nlb, const float* __restrict__ fcw,
                       const float* __restrict__ fcb, float* __restrict__ out) {
    __shared__ float sn[128];
    int e = blockIdx.x, lane = threadIdx.x;   // 64 threads
    float x0 = message[e * 3200 + lane];
    float x1 = message[e * 3200 + 64 + lane];
    float sm = x0 + x1, sq = x0 * x0 + x1 * x1;
    #pragma unroll
    for (int m = 1; m < 64; m <<= 1) {
        sm += __shfl_xor(sm, m, 64);
        sq += __shfl_xor(sq, m, 64);
    }
    float mean = sm * (1.f / 128.f);
    float rstd = rsqrtf(sq * (1.f / 128.f) - mean * mean + 1e-5f);
    sn[lane]      = (x0 - mean) * rstd * nlg[lane]      + nlb[lane];
    sn[lane + 64] = (x1 - mean) * rstd * nlg[lane + 64] + nlb[lane + 64];
    __syncthreads();
    float o0 = fcb[lane], o1 = fcb[lane + 64];
    for (int j = 0; j < 128; ++j) {
        float nj = sn[j];
        o0 += nj * fcw[j * 128 + lane];
        o1 += nj * fcw[j * 128 + lane + 64];
    }
    out[e * 3200 + lane]      = o0 / (1.f + __expf(-o0));
    out[e * 3200 + 64 + lane] = o1 / (1.f + __expf(-o1));
}

// ---------------- kernC: MFMA expert MLPs (2 edges/block) + from_grid ----------------
__global__ __launch_bounds__(256, 2) void kernC(
        const __hip_bfloat16* __restrict__ nout_ro, const float* __restrict__ gate,
        const __hip_bfloat16* __restrict__ w1s, const __hip_bfloat16* __restrict__ w2s,
        const float* __restrict__ b1p, const float* __restrict__ b2,
        const float* __restrict__ fg, float* __restrict__ out) {

    __shared__ __align__(16) char smem[128 * 272 + 64 * 272];   // sX 34816 + sS 17408
    __shared__ float sGB2[2][128];
    char* sXb = smem;                 // X[n=128][c=128] bf16, row stride 272 B
    char* sSb = smem + 128 * 272;     // S[n=64][h=128] bf16, row stride 272 B
    float* sAcc = (float*)smem;       // epilogue overlay: acc[s=64][c], row stride 132 fl

    const int e0 = blockIdx.x * 2;
    const int tid = threadIdx.x;
    const int w = tid >> 6, lane = tid & 63;
    const int quad = lane >> 4, col = lane & 15;
    const int htB = (w >> 1) * 4;      // M-tile base
    const int stB = (w & 1) * 2;       // N-tile base

    // ---- stage X: pure bf16 copy ----
    for (int i = tid; i < 2048; i += 256) {
        int n = i >> 4, c16 = i & 15;
        bf16x8 v = *(const bf16x8*)(nout_ro + (size_t)(e0 * 64 + n) * 128 + c16 * 8);
        *(bf16x8*)(sXb + n * 272 + c16 * 16) = v;
    }
    {   // gate-weighted b2 per edge
        int e_l = tid >> 7, c = tid & 127;
        float s = 0.f;
        #pragma unroll
        for (int ex = 0; ex < 8; ++ex) s += gate[(e0 + e_l) * 8 + ex] * b2[ex * 128 + c];
        sGB2[e_l][c] = s;
    }
    __syncthreads();

    floatx4 accT[2][4][2];
    #pragma unroll
    for (int e = 0; e < 2; ++e)
        #pragma unroll
        for (int m = 0; m < 4; ++m)
            #pragma unroll
            for (int n2 = 0; n2 < 2; ++n2) accT[e][m][n2] = (floatx4)0.f;

    for (int ex = 0; ex < NEXP_; ++ex) {
        for (int hb = 0; hb < 4; ++hb) {
            for (int ph = 0; ph < 2; ++ph) {
                const float gv = gate[(e0 + ph) * 8 + ex];
                floatx4 accP[4][2];
                #pragma unroll
                for (int mt = 0; mt < 4; ++mt) {
                    int h = hb * 128 + (htB + mt) * 16 + quad * 4;
                    float4 bv = *(const float4*)(b1p + ex * 512 + h);
                    #pragma unroll
                    for (int nt = 0; nt < 2; ++nt) {
                        accP[mt][nt][0] = bv.x; accP[mt][nt][1] = bv.y;
                        accP[mt][nt][2] = bv.z; accP[mt][nt][3] = bv.w;
                    }
                }
                #pragma unroll
                for (int kt = 0; kt < 4; ++kt) {
                    bf16x8 a[4], b[2];
                    #pragma unroll
                    for (int mt = 0; mt < 4; ++mt)
                        a[mt] = *(const bf16x8*)(w1s + (size_t)((ex*32 + hb*8 + htB + mt)*4 + kt)*512 + lane*8);
                    #pragma unroll
                    for (int nt = 0; nt < 2; ++nt) {
                        int n = ph * 64 + (stB + nt) * 16 + col;
                        b[nt] = *(const bf16x8*)(sXb + n * 272 + kt * 64 + quad * 16);
                    }
                    #pragma unroll
                    for (int mt = 0; mt < 4; ++mt)
                        #pragma unroll
                        for (int nt = 0; nt < 2; ++nt)
                            accP[mt][nt] = __builtin_amdgcn_mfma_f32_16x16x32_bf16(a[mt], b[nt], accP[mt][nt], 0, 0, 0);
                }
                #pragma unroll
                for (int mt = 0; mt < 4; ++mt) {
                    int hl = (htB + mt) * 16 + quad * 4;
                    #pragma unroll
                    for (int nt = 0; nt < 2; ++nt) {
                        int nl = (stB + nt) * 16 + col;
                        bf16x4 sv;
                        #pragma unroll
                        for (int r = 0; r < 4; ++r) {
                            float p = accP[mt][nt][r];
                            sv[r] = (__bf16)(gv * p / (1.f + __expf(-p)));
                        }
                        *(bf16x4*)(sSb + nl * 272 + hl * 2) = sv;
                    }
                }
                __syncthreads();
                #pragma unroll
                for (int kt = 0; kt < 4; ++kt) {
                    bf16x8 a[4], b[2];
                    #pragma unroll
                    for (int mt = 0; mt < 4; ++mt)
                        a[mt] = *(const bf16x8*)(w2s + (size_t)((ex*8 + htB + mt)*16 + hb*4 + kt)*512 + lane*8);
                    #pragma unroll
                    for (int nt = 0; nt < 2; ++nt) {
                        int nl = (stB + nt) * 16 + col;
                        b[nt] = *(const bf16x8*)(sSb + nl * 272 + kt * 64 + quad * 16);
                    }
                    #pragma unroll
                    for (int mt = 0; mt < 4; ++mt)
                        #pragma unroll
                        for (int nt = 0; nt < 2; ++nt)
                            accT[ph][mt][nt] = __builtin_amdgcn_mfma_f32_16x16x32_bf16(a[mt], b[nt], accT[ph][mt][nt], 0, 0, 0);
                }
                __syncthreads();
            }
        }
    }

    for (int e = 0; e < 2; ++e) {
        #pragma unroll
        for (int mt = 0; mt < 4; ++mt) {
            int c = (htB + mt) * 16 + quad * 4;
            float4 gb = *(const float4*)(&sGB2[e][c]);
            #pragma unroll
            for (int nt = 0; nt < 2; ++nt) {
                int nl = (stB + nt) * 16 + col;
                float4 v;
                v.x = accT[e][mt][nt][0] + gb.x;
                v.y = accT[e][mt][nt][1] + gb.y;
                v.z = accT[e][mt][nt][2] + gb.z;
                v.w = accT[e][mt][nt][3] + gb.w;
                *(float4*)(sAcc + nl * 132 + c) = v;
            }
        }
        __syncthreads();
        for (int idx = tid; idx < 768; idx += 256) {
            int l = 1 + (idx >> 5);
            int c4 = (idx & 31) * 4;
            float4 a4 = {0.f, 0.f, 0.f, 0.f};
            const float* fgr = fg + l * 64;
            for (int s = 0; s < 64; ++s) {
                float f = fgr[s];
                const float* row = sAcc + s * 132 + c4;
                a4.x += f * row[0]; a4.y += f * row[1]; a4.z += f * row[2]; a4.w += f * row[3];
            }
            *(float4*)(out + (size_t)(e0 + e) * 3200 + l * 128 + c4) = a4;
        }
        __syncthreads();
    }
}

extern "C" void kernel_launch(void* const* d_in, const int* in_sizes, int n_in,
                              void* d_out, int out_size, void* d_ws, size_t ws_size,
                              hipStream_t stream) {
    (void)in_sizes; (void)n_in; (void)out_size; (void)ws_size;
    const float* message = (const float*)d_in[0];
    const float* gate    = (const float*)d_in[1];
    // d_in[2] = batch (unused by reference math)
    const float* ln1g = (const float*)d_in[3];
    const float* ln1b = (const float*)d_in[4];
    const float* wq   = (const float*)d_in[5];
    const float* bq   = (const float*)d_in[6];
    const float* wk   = (const float*)d_in[7];
    const float* bk   = (const float*)d_in[8];
    const float* wv   = (const float*)d_in[9];
    const float* bv   = (const float*)d_in[10];
    const float* nlg  = (const float*)d_in[11];
    const float* nlb  = (const float*)d_in[12];
    const float* fcw  = (const float*)d_in[13];
    const float* fcb  = (const float*)d_in[14];
    const float* elng = (const float*)d_in[15];
    const float* elnb = (const float*)d_in[16];
    const float* w1   = (const float*)d_in[17];
    const float* b1   = (const float*)d_in[18];
    const float* w2   = (const float*)d_in[19];
    const float* b2   = (const float*)d_in[20];
    const float* tg   = (const float*)d_in[21];
    const float* fg   = (const float*)d_in[22];
    const float* pe   = (const float*)d_in[23];
    float* ws  = (float*)d_ws;
    float* out = (float*)d_out;
    __hip_bfloat16* gtfp = (__hip_bfloat16*)(ws + OFF_GTF);
    __hip_bfloat16* wvtf = (__hip_bfloat16*)(ws + OFF_WVTF);
    __hip_bfloat16* w1s  = (__hip_bfloat16*)(ws + OFF_W1S);
    __hip_bfloat16* w2s  = (__hip_bfloat16*)(ws + OFF_W2S);
    __hip_bfloat16* gg   = (__hip_bfloat16*)(ws + OFF_GG);
    __hip_bfloat16* nout = (__hip_bfloat16*)(ws + OFF_NOUT);

    prep1<<<dim3(65), dim3(256), 0, stream>>>(wq, bq, wk, bk, pe, ws);
    prep2<<<dim3(8), dim3(256), 0, stream>>>(elnb, w1, b1, ws);
    prepSwz<<<dim3(4096), dim3(256), 0, stream>>>(elng, w1, w2, w1s, w2s);
    prepSwzA<<<dim3(128), dim3(256), 0, stream>>>(ws, wv, gtfp, wvtf);
    kernG<<<dim3(E_), dim3(256), 0, stream>>>(message, tg, gg);
    kernA<<<dim3(E_), dim3(256), 0, stream>>>(gg, ln1g, ln1b, bv, ws, gtfp, wvtf, nout);
    kernL0<<<dim3(E_), dim3(64), 0, stream>>>(message, nlg, nlb, fcw, fcb, out);
    kernC<<<dim3(E_ / 2), dim3(256), 0, stream>>>(nout, gate, w1s, w2s,
                                                  ws + OFF_B1P, b2, fg, out);
}

// Round 6
// 354.271 us; speedup vs baseline: 8.5895x; 1.2666x over previous
//
#include <hip/hip_runtime.h>
#include <hip/hip_bf16.h>

#define E_ 1024
#define L_ 25
#define S_ 64
#define C_ 128
#define H_ 512
#define NEXP_ 8

// workspace float offsets
#define OFF_W     0         // 128 (wk @ bq fold, for mw[t])
#define OFF_PEDOT 128       // 64*64 -> 4224
#define OFF_B1P   4224      // 8*512 -> 8320
#define OFF_GTF   8320      // 16384 bf16 (G frags) = 8192 fl -> 16512
#define OFF_WVTF  16512     // 16384 bf16 (Wv^T frags) -> 24704
#define OFF_TGF   24704     // 2048 bf16 (to_grid A-frags) = 1024 fl -> 25728
#define OFF_G     25728     // 128*128 fp32 -> 42112
#define OFF_W1S   42112     // 524288 bf16 = 262144 fl -> 304256
#define OFF_W2S   304256    // 524288 bf16 -> 566400
#define OFF_NOUT  566400    // 1024*64*128 bf16 = 4194304 fl -> 4760704 (~19 MB)

typedef float floatx4 __attribute__((ext_vector_type(4)));
typedef __bf16 bf16x8 __attribute__((ext_vector_type(8)));
typedef __bf16 bf16x4 __attribute__((ext_vector_type(4)));

// ---------------- prep1: G = Wq Wk^T, w fold, pedot ----------------
__global__ void prep1(const float* __restrict__ wq, const float* __restrict__ bq,
                      const float* __restrict__ wk, const float* __restrict__ bk,
                      const float* __restrict__ pe, float* __restrict__ ws) {
    int b = blockIdx.x, tid = threadIdx.x;
    (void)bk;
    if (b < 64) {
        int a = b * 2 + (tid >> 7);
        int col = tid & 127;
        const float* ra = wq + a * C_;
        const float* rb = wk + col * C_;
        float acc = 0.f;
        for (int c = 0; c < C_; ++c) acc += ra[c] * rb[c];
        ws[OFF_G + a * C_ + col] = acc;
    } else {
        if (tid < 128) {   // w[j] = wk_row_j . bq   (mw[t] = m_t . w)
            float acc = 0.f; const float* r = wk + tid * C_;
            for (int c = 0; c < C_; ++c) acc += r[c] * bq[c];
            ws[OFF_W + tid] = acc;
        }
        for (int idx = tid; idx < 64 * 64; idx += 256) {
            int s = idx >> 6, t = idx & 63;
            ws[OFF_PEDOT + idx] = pe[s*3]*pe[t*3] + pe[s*3+1]*pe[t*3+1] + pe[s*3+2]*pe[t*3+2];
        }
    }
}

// ---------------- prep2: b1p = elnb @ w1 + b1 (fp32) ----------------
__global__ void prep2(const float* __restrict__ elnb, const float* __restrict__ w1,
                      const float* __restrict__ b1, float* __restrict__ ws) {
    int i = blockIdx.x, tid = threadIdx.x;
    for (int h = tid; h < H_; h += 256) {
        float acc = b1[i * H_ + h];
        const float* wcol = w1 + i * C_ * H_ + h;
        for (int c = 0; c < C_; ++c) acc += elnb[i * C_ + c] * wcol[c * H_];
        ws[OFF_B1P + i * H_ + h] = acc;
    }
}

// ---------------- prepSwz: LN-folded w1 / w2 -> MFMA A-frag order (bf16) ----------------
__global__ void prepSwz(const float* __restrict__ elng, const float* __restrict__ w1,
                        const float* __restrict__ w2,
                        __hip_bfloat16* __restrict__ w1s, __hip_bfloat16* __restrict__ w2s) {
    int idx = blockIdx.x * 256 + threadIdx.x;
    if (idx < 524288) {
        int f = idx >> 9, r = idx & 511;
        int lane = r >> 3, j = r & 7;
        int kt = f & 3, htg = (f >> 2) & 31, ex = f >> 7;
        int c = kt * 32 + (lane >> 4) * 8 + j;
        int h = htg * 16 + (lane & 15);
        w1s[idx] = __float2bfloat16(elng[ex * 128 + c] * w1[ex * 65536 + c * 512 + h]);
    } else {
        int i2 = idx - 524288;
        int f = i2 >> 9, r = i2 & 511;
        int lane = r >> 3, j = r & 7;
        int ktg = f & 15, ctg = (f >> 4) & 7, ex = f >> 7;
        int h = ktg * 32 + (lane >> 4) * 8 + j;
        int c = ctg * 16 + (lane & 15);
        w2s[i2] = __float2bfloat16(w2[ex * 65536 + h * 128 + c]);
    }
}

// ---------------- prepSwzA: G, Wv^T -> B-frag order; to_grid -> A-frag order ----------------
// B-frag: Brow[n][k], frag f = Nt*4+kt, elem lane*8+j = Brow[Nt*16+(lane&15)][kt*32+(lane>>4)*8+j]
// A-frag: frag mt, elem lane*8+j = A[mt*16+(lane&15)][(lane>>4)*8+j]
__global__ void prepSwzA(const float* __restrict__ ws, const float* __restrict__ wv,
                         const float* __restrict__ tg,
                         __hip_bfloat16* __restrict__ gtf, __hip_bfloat16* __restrict__ wvtf,
                         __hip_bfloat16* __restrict__ tgf) {
    int idx = blockIdx.x * 256 + threadIdx.x;   // < 34816
    if (idx < 32768) {
        int i2 = idx & 16383;
        int f = i2 >> 9, r = i2 & 511;    // f 0..31
        int lane = r >> 3, j = r & 7;
        int kt = f & 3, Nt = f >> 2;      // Nt 0..7
        int k = kt * 32 + (lane >> 4) * 8 + j;
        int n = Nt * 16 + (lane & 15);
        if (idx < 16384) {
            gtf[i2] = __float2bfloat16(ws[OFF_G + k * 128 + n]);   // Brow[j][c] = G[c][j]
        } else {
            wvtf[i2] = __float2bfloat16(wv[k * 128 + n]);          // Brow[c][j] = wv[j][c]
        }
    } else {
        int i3 = idx - 32768;             // < 2048
        int f = i3 >> 9, r = i3 & 511;    // f = mt 0..3
        int lane = r >> 3, j = r & 7;
        int m = f * 16 + (lane & 15);
        int k = (lane >> 4) * 8 + j;
        tgf[i3] = (k < 25) ? __float2bfloat16(tg[m * 25 + k]) : __float2bfloat16(0.f);
    }
}

// ---------------- kernA: fused grid-proj + LN + MFMA attention per edge ----------------
// Conventions (verified): D[m][n] = sum_k A[m][k]*Brow[n][k]
//   A-frag: row lane&15, bytes kt*64 + quad*16 of a row-major K-contiguous row
//   B-frag: same pattern on Brow;  C/D: n = Ntbase + col, m = Mtbase + quad*4 + reg
__global__ __launch_bounds__(256) void kernA(
        const float* __restrict__ message, const float* __restrict__ ln1g,
        const float* __restrict__ ln1b, const float* __restrict__ bv,
        const float* __restrict__ ws_ro,
        const __hip_bfloat16* __restrict__ gtf, const __hip_bfloat16* __restrict__ wvtf,
        const __hip_bfloat16* __restrict__ tgf,
        __hip_bfloat16* __restrict__ nout) {
    __shared__ __align__(16) char sA[64 * 272];    // g rows -> m rows [s][c]
    __shared__ __align__(16) char sB[64 * 272];    // (msg fp32 stage) -> z -> p -> out rows
    __shared__ __align__(16) char sC[128 * 144];   // (msgT bf16) -> sc fp32 [64][68] -> vT rows
    __shared__ __align__(16) float sStP[512];
    __shared__ __align__(16) float sSt2[128];
    __shared__ float sMw[64];

    const int e = blockIdx.x, tid = threadIdx.x;
    const int w = tid >> 6, lane = tid & 63, quad = lane >> 4, col = lane & 15;

    // ---- 0a. stage msg fp32 (coalesced) into sB overlay ----
    float* sMsgF = (float*)sB;
    for (int i = tid; i < 3200; i += 256) sMsgF[i] = message[(size_t)e * 3200 + i];
    __syncthreads();   // S0a

    // ---- 0b. transpose+cvt+pad: msgT[c][l] bf16, row stride 80 B, l=25..31 zero ----
    char* sMt = sC;
    for (int i = tid; i < 4096; i += 256) {
        int c = i >> 5, l = i & 31;
        float v = (l < 25) ? sMsgF[l * 128 + c] : 0.f;
        *(__hip_bfloat16*)(sMt + c * 80 + l * 2) = __float2bfloat16(v);
    }
    __syncthreads();   // S0b

    // ---- 0c. g = to_grid @ msgT  (K=32 MFMA) -> sA rows bf16 ----
    {
        floatx4 accG[4][2];
        #pragma unroll
        for (int mt = 0; mt < 4; ++mt) { accG[mt][0] = (floatx4)0.f; accG[mt][1] = (floatx4)0.f; }
        bf16x8 a[4], b[2];
        #pragma unroll
        for (int mt = 0; mt < 4; ++mt) a[mt] = *(const bf16x8*)(tgf + mt * 512 + lane * 8);
        #pragma unroll
        for (int nt = 0; nt < 2; ++nt)
            b[nt] = *(const bf16x8*)(sMt + ((2 * w + nt) * 16 + col) * 80 + quad * 16);
        #pragma unroll
        for (int mt = 0; mt < 4; ++mt)
            #pragma unroll
            for (int nt = 0; nt < 2; ++nt)
                accG[mt][nt] = __builtin_amdgcn_mfma_f32_16x16x32_bf16(a[mt], b[nt], accG[mt][nt], 0, 0, 0);
        #pragma unroll
        for (int mt = 0; mt < 4; ++mt)
            #pragma unroll
            for (int nt = 0; nt < 2; ++nt) {
                int c = (2 * w + nt) * 16 + col;
                #pragma unroll
                for (int reg = 0; reg < 4; ++reg)
                    ((__hip_bfloat16*)(sA + (mt * 16 + quad * 4 + reg) * 272))[c] =
                        __float2bfloat16(accG[mt][nt][reg]);
            }
    }
    __syncthreads();   // S0c

    // ---- 1. LN in place on sA rows ----
    {
        float g1a = ln1g[lane], g1b = ln1g[lane + 64];
        float b1a = ln1b[lane], b1b = ln1b[lane + 64];
        for (int r = 0; r < 16; ++r) {
            int s = w * 16 + r;
            __hip_bfloat16* mr = (__hip_bfloat16*)(sA + s * 272);
            float x0 = __bfloat162float(mr[lane]);
            float x1 = __bfloat162float(mr[lane + 64]);
            float sm = x0 + x1, sq = x0 * x0 + x1 * x1;
            #pragma unroll
            for (int m = 1; m < 64; m <<= 1) {
                sm += __shfl_xor(sm, m, 64);
                sq += __shfl_xor(sq, m, 64);
            }
            float mean = sm * (1.f / 128.f);
            float rstd = rsqrtf(sq * (1.f / 128.f) - mean * mean + 1e-5f);
            mr[lane]      = __float2bfloat16((x0 - mean) * rstd * g1a + b1a);
            mr[lane + 64] = __float2bfloat16((x1 - mean) * rstd * g1b + b1b);
        }
    }
    __syncthreads();   // S1

    // ---- 2. mw[t] = m_t . w ----
    {
        int t = tid >> 2, part = tid & 3;
        const __hip_bfloat16* mr = (const __hip_bfloat16*)(sA + t * 272) + part * 32;
        const float* wv_ = ws_ro + OFF_W + part * 32;
        float acc = 0.f;
        #pragma unroll
        for (int k = 0; k < 32; ++k) acc += __bfloat162float(mr[k]) * wv_[k];
        acc += __shfl_xor(acc, 1, 64);
        acc += __shfl_xor(acc, 2, 64);
        if (part == 0) sMw[t] = acc;
    }

    // ---- 3. z = m @ G (B-frags) ----
    {
        floatx4 accZ[4][2];
        #pragma unroll
        for (int mt = 0; mt < 4; ++mt) { accZ[mt][0] = (floatx4)0.f; accZ[mt][1] = (floatx4)0.f; }
        #pragma unroll
        for (int kt = 0; kt < 4; ++kt) {
            bf16x8 a[4], b[2];
            #pragma unroll
            for (int mt = 0; mt < 4; ++mt)
                a[mt] = *(const bf16x8*)(sA + (mt * 16 + col) * 272 + kt * 64 + quad * 16);
            #pragma unroll
            for (int nt = 0; nt < 2; ++nt)
                b[nt] = *(const bf16x8*)(gtf + ((2 * w + nt) * 4 + kt) * 512 + lane * 8);
            #pragma unroll
            for (int mt = 0; mt < 4; ++mt)
                #pragma unroll
                for (int nt = 0; nt < 2; ++nt)
                    accZ[mt][nt] = __builtin_amdgcn_mfma_f32_16x16x32_bf16(a[mt], b[nt], accZ[mt][nt], 0, 0, 0);
        }
        #pragma unroll
        for (int mt = 0; mt < 4; ++mt)
            #pragma unroll
            for (int nt = 0; nt < 2; ++nt) {
                int j = (2 * w + nt) * 16 + col;
                #pragma unroll
                for (int reg = 0; reg < 4; ++reg)
                    ((__hip_bfloat16*)(sB + (mt * 16 + quad * 4 + reg) * 272))[j] =
                        __float2bfloat16(accZ[mt][nt][reg]);
            }
    }
    __syncthreads();   // S2

    // ---- 4. sc = z @ m^T ----
    {
        floatx4 accS[4];
        #pragma unroll
        for (int mt = 0; mt < 4; ++mt) accS[mt] = (floatx4)0.f;
        #pragma unroll
        for (int kt = 0; kt < 4; ++kt) {
            bf16x8 a[4];
            #pragma unroll
            for (int mt = 0; mt < 4; ++mt)
                a[mt] = *(const bf16x8*)(sB + (mt * 16 + col) * 272 + kt * 64 + quad * 16);
            bf16x8 b = *(const bf16x8*)(sA + (w * 16 + col) * 272 + kt * 64 + quad * 16);
            #pragma unroll
            for (int mt = 0; mt < 4; ++mt)
                accS[mt] = __builtin_amdgcn_mfma_f32_16x16x32_bf16(a[mt], b, accS[mt], 0, 0, 0);
        }
        float* sc = (float*)sC;
        #pragma unroll
        for (int mt = 0; mt < 4; ++mt)
            #pragma unroll
            for (int reg = 0; reg < 4; ++reg)
                sc[(mt * 16 + quad * 4 + reg) * 68 + w * 16 + col] = accS[mt][reg];
    }
    __syncthreads();   // S3

    // ---- 5. softmax rows -> p rows bf16 ----
    {
        const float scale = 0.08737040566610379f;   // 1/sqrt(131)
        const float* sc = (const float*)sC;
        const float* pd = ws_ro + OFF_PEDOT;
        for (int r = 0; r < 16; ++r) {
            int s = w * 16 + r;
            float x = sc[s * 68 + lane] + sMw[lane] + pd[s * 64 + lane];
            float mx = x;
            #pragma unroll
            for (int m = 1; m < 64; m <<= 1) mx = fmaxf(mx, __shfl_xor(mx, m, 64));
            float p = __expf((x - mx) * scale);
            float sm = p;
            #pragma unroll
            for (int m = 1; m < 64; m <<= 1) sm += __shfl_xor(sm, m, 64);
            float rs = __builtin_amdgcn_rcpf(sm);
            ((__hip_bfloat16*)(sB + s * 272))[lane] = __float2bfloat16(p * rs);
        }
    }
    __syncthreads();   // S4

    // ---- 6. v = m @ Wv^T + bv -> vT rows [c][t] ----
    {
        floatx4 accV[4][2];
        #pragma unroll
        for (int mt = 0; mt < 4; ++mt) { accV[mt][0] = (floatx4)0.f; accV[mt][1] = (floatx4)0.f; }
        #pragma unroll
        for (int kt = 0; kt < 4; ++kt) {
            bf16x8 a[4], b[2];
            #pragma unroll
            for (int mt = 0; mt < 4; ++mt)
                a[mt] = *(const bf16x8*)(sA + (mt * 16 + col) * 272 + kt * 64 + quad * 16);
            #pragma unroll
            for (int nt = 0; nt < 2; ++nt)
                b[nt] = *(const bf16x8*)(wvtf + ((2 * w + nt) * 4 + kt) * 512 + lane * 8);
            #pragma unroll
            for (int mt = 0; mt < 4; ++mt)
                #pragma unroll
                for (int nt = 0; nt < 2; ++nt)
                    accV[mt][nt] = __builtin_amdgcn_mfma_f32_16x16x32_bf16(a[mt], b[nt], accV[mt][nt], 0, 0, 0);
        }
        #pragma unroll
        for (int nt = 0; nt < 2; ++nt) {
            int c = (2 * w + nt) * 16 + col;
            float bvv = bv[c];
            #pragma unroll
            for (int mt = 0; mt < 4; ++mt) {
                bf16x4 pk;
                #pragma unroll
                for (int reg = 0; reg < 4; ++reg)
                    pk[reg] = (__bf16)(accV[mt][nt][reg] + bvv);
                *(bf16x4*)(sC + c * 144 + (mt * 16 + quad * 4) * 2) = pk;
            }
        }
    }
    __syncthreads();   // S5

    // ---- 7. out = p @ vT ----
    floatx4 accO[4][2];
    #pragma unroll
    for (int mt = 0; mt < 4; ++mt) { accO[mt][0] = (floatx4)0.f; accO[mt][1] = (floatx4)0.f; }
    #pragma unroll
    for (int kt = 0; kt < 2; ++kt) {
        bf16x8 a[4], b[2];
        #pragma unroll
        for (int mt = 0; mt < 4; ++mt)
            a[mt] = *(const bf16x8*)(sB + (mt * 16 + col) * 272 + kt * 64 + quad * 16);
        #pragma unroll
        for (int nt = 0; nt < 2; ++nt)
            b[nt] = *(const bf16x8*)(sC + ((2 * w + nt) * 16 + col) * 144 + kt * 64 + quad * 16);
        #pragma unroll
        for (int mt = 0; mt < 4; ++mt)
            #pragma unroll
            for (int nt = 0; nt < 2; ++nt)
                accO[mt][nt] = __builtin_amdgcn_mfma_f32_16x16x32_bf16(a[mt], b[nt], accO[mt][nt], 0, 0, 0);
    }

    // ---- 8. LN partials ----
    #pragma unroll
    for (int mt = 0; mt < 4; ++mt)
        #pragma unroll
        for (int reg = 0; reg < 4; ++reg) {
            float v0 = accO[mt][0][reg], v1 = accO[mt][1][reg];
            float sm = v0 + v1, sq = v0 * v0 + v1 * v1;
            #pragma unroll
            for (int m = 1; m < 16; m <<= 1) {
                sm += __shfl_xor(sm, m, 64);
                sq += __shfl_xor(sq, m, 64);
            }
            if (col == 0) {
                int s = mt * 16 + quad * 4 + reg;
                sStP[(s * 4 + w) * 2]     = sm;
                sStP[(s * 4 + w) * 2 + 1] = sq;
            }
        }
    __syncthreads();   // S6
    if (tid < 64) {
        float sm = 0.f, sq = 0.f;
        #pragma unroll
        for (int k = 0; k < 4; ++k) {
            sm += sStP[(tid * 4 + k) * 2];
            sq += sStP[(tid * 4 + k) * 2 + 1];
        }
        float mean = sm * (1.f / 128.f);
        float rstd = rsqrtf(sq * (1.f / 128.f) - mean * mean + 1e-5f);
        sSt2[tid * 2] = mean; sSt2[tid * 2 + 1] = rstd;
    }
    __syncthreads();   // S7

    // ---- 9. normalize -> out rows bf16 ----
    #pragma unroll
    for (int mt = 0; mt < 4; ++mt)
        #pragma unroll
        for (int reg = 0; reg < 4; ++reg) {
            int s = mt * 16 + quad * 4 + reg;
            float mean = sSt2[s * 2], rstd = sSt2[s * 2 + 1];
            #pragma unroll
            for (int nt = 0; nt < 2; ++nt) {
                int c = (2 * w + nt) * 16 + col;
                ((__hip_bfloat16*)(sB + s * 272))[c] =
                    __float2bfloat16((accO[mt][nt][reg] - mean) * rstd);
            }
        }
    __syncthreads();   // S8

    // ---- 10. coalesced store ----
    for (int i = tid; i < 1024; i += 256) {
        int row = i >> 4, c16 = i & 15;
        bf16x8 v = *(const bf16x8*)(sB + row * 272 + c16 * 16);
        *(bf16x8*)(nout + (size_t)e * 8192 + row * 128 + c16 * 8) = v;
    }
}

// ---------------- kernL0: l=0 scalar branch -> output row 0 ----------------
__global__ void kernL0(const float* __restrict__ message, const float* __restrict__ nlg,
                       const float* __restrict__ nlb, const float* __restrict__ fcw,
                       const float* __restrict__ fcb, float* __restrict__ out) {
    __shared__ float sn[128];
    int e = blockIdx.x, lane = threadIdx.x;   // 64 threads
    float x0 = message[e * 3200 + lane];
    float x1 = message[e * 3200 + 64 + lane];
    float sm = x0 + x1, sq = x0 * x0 + x1 * x1;
    #pragma unroll
    for (int m = 1; m < 64; m <<= 1) {
        sm += __shfl_xor(sm, m, 64);
        sq += __shfl_xor(sq, m, 64);
    }
    float mean = sm * (1.f / 128.f);
    float rstd = rsqrtf(sq * (1.f / 128.f) - mean * mean + 1e-5f);
    sn[lane]      = (x0 - mean) * rstd * nlg[lane]      + nlb[lane];
    sn[lane + 64] = (x1 - mean) * rstd * nlg[lane + 64] + nlb[lane + 64];
    __syncthreads();
    float o0 = fcb[lane], o1 = fcb[lane + 64];
    for (int j = 0; j < 128; ++j) {
        float nj = sn[j];
        o0 += nj * fcw[j * 128 + lane];
        o1 += nj * fcw[j * 128 + lane + 64];
    }
    out[e * 3200 + lane]      = o0 * __builtin_amdgcn_rcpf(1.f + __expf(-o0));
    out[e * 3200 + 64 + lane] = o1 * __builtin_amdgcn_rcpf(1.f + __expf(-o1));
}

// ---------------- kernC: MFMA expert MLPs (2 edges/block, frag-reuse) + from_grid ----------------
__global__ __launch_bounds__(256, 2) void kernC(
        const __hip_bfloat16* __restrict__ nout_ro, const float* __restrict__ gate,
        const __hip_bfloat16* __restrict__ w1s, const __hip_bfloat16* __restrict__ w2s,
        const float* __restrict__ b1p, const float* __restrict__ b2,
        const float* __restrict__ fg, float* __restrict__ out) {

    __shared__ __align__(16) char smem[128 * 272 + 128 * 272];   // sX + sS(both ph) = 69632
    __shared__ float sGB2[2][128];
    char* sXb = smem;                 // X[n=128][c=128] bf16, row stride 272 B
    char* sSb = smem + 128 * 272;     // S[n=128][h=128] bf16 (rows ph*64+s)
    float* sAcc = (float*)smem;       // epilogue overlay

    const int e0 = blockIdx.x * 2;
    const int tid = threadIdx.x;
    const int w = tid >> 6, lane = tid & 63;
    const int quad = lane >> 4, col = lane & 15;
    const int htB = (w >> 1) * 4;      // M-tile base
    const int stB = (w & 1) * 2;       // N-tile base

    // ---- stage X: pure bf16 copy ----
    for (int i = tid; i < 2048; i += 256) {
        int n = i >> 4, c16 = i & 15;
        bf16x8 v = *(const bf16x8*)(nout_ro + (size_t)(e0 * 64 + n) * 128 + c16 * 8);
        *(bf16x8*)(sXb + n * 272 + c16 * 16) = v;
    }
    {   // gate-weighted b2 per edge
        int e_l = tid >> 7, c = tid & 127;
        float s = 0.f;
        #pragma unroll
        for (int ex = 0; ex < 8; ++ex) s += gate[(e0 + e_l) * 8 + ex] * b2[ex * 128 + c];
        sGB2[e_l][c] = s;
    }
    __syncthreads();

    floatx4 accT[2][4][2];
    #pragma unroll
    for (int e = 0; e < 2; ++e)
        #pragma unroll
        for (int m = 0; m < 4; ++m)
            #pragma unroll
            for (int n2 = 0; n2 < 2; ++n2) accT[e][m][n2] = (floatx4)0.f;

    for (int ex = 0; ex < NEXP_; ++ex) {
        const float gv0 = gate[e0 * 8 + ex];
        const float gv1 = gate[e0 * 8 + 8 + ex];
        for (int hb = 0; hb < 4; ++hb) {
            // ---- w1 A-frags + bias, loaded ONCE for both phases ----
            bf16x8 a1[4][4];
            #pragma unroll
            for (int mt = 0; mt < 4; ++mt)
                #pragma unroll
                for (int kt = 0; kt < 4; ++kt)
                    a1[mt][kt] = *(const bf16x8*)(w1s + (size_t)((ex*32 + hb*8 + htB + mt)*4 + kt)*512 + lane*8);
            float4 bias[4];
            #pragma unroll
            for (int mt = 0; mt < 4; ++mt)
                bias[mt] = *(const float4*)(b1p + ex * 512 + hb * 128 + (htB + mt) * 16 + quad * 4);

            #pragma unroll
            for (int ph = 0; ph < 2; ++ph) {
                const float gv = ph ? gv1 : gv0;
                floatx4 accP[4][2];
                #pragma unroll
                for (int mt = 0; mt < 4; ++mt)
                    #pragma unroll
                    for (int nt = 0; nt < 2; ++nt) {
                        accP[mt][nt][0] = bias[mt].x; accP[mt][nt][1] = bias[mt].y;
                        accP[mt][nt][2] = bias[mt].z; accP[mt][nt][3] = bias[mt].w;
                    }
                #pragma unroll
                for (int kt = 0; kt < 4; ++kt) {
                    bf16x8 b[2];
                    #pragma unroll
                    for (int nt = 0; nt < 2; ++nt) {
                        int n = ph * 64 + (stB + nt) * 16 + col;
                        b[nt] = *(const bf16x8*)(sXb + n * 272 + kt * 64 + quad * 16);
                    }
                    #pragma unroll
                    for (int mt = 0; mt < 4; ++mt)
                        #pragma unroll
                        for (int nt = 0; nt < 2; ++nt)
                            accP[mt][nt] = __builtin_amdgcn_mfma_f32_16x16x32_bf16(a1[mt][kt], b[nt], accP[mt][nt], 0, 0, 0);
                }
                // ---- silu * gate -> S rows ph*64+s (rcp, not IEEE div) ----
                #pragma unroll
                for (int mt = 0; mt < 4; ++mt) {
                    int hl = (htB + mt) * 16 + quad * 4;
                    #pragma unroll
                    for (int nt = 0; nt < 2; ++nt) {
                        int nl = ph * 64 + (stB + nt) * 16 + col;
                        bf16x4 sv;
                        #pragma unroll
                        for (int r = 0; r < 4; ++r) {
                            float p = accP[mt][nt][r];
                            sv[r] = (__bf16)(gv * p * __builtin_amdgcn_rcpf(1.f + __expf(-p)));
                        }
                        *(bf16x4*)(sSb + nl * 272 + hl * 2) = sv;
                    }
                }
            }
            __syncthreads();   // S for both phases ready

            // ---- w2 A-frags loaded ONCE ----
            bf16x8 a2[4][4];
            #pragma unroll
            for (int mt = 0; mt < 4; ++mt)
                #pragma unroll
                for (int kt = 0; kt < 4; ++kt)
                    a2[mt][kt] = *(const bf16x8*)(w2s + (size_t)((ex*8 + htB + mt)*16 + hb*4 + kt)*512 + lane*8);
            #pragma unroll
            for (int ph = 0; ph < 2; ++ph) {
                #pragma unroll
                for (int kt = 0; kt < 4; ++kt) {
                    bf16x8 b[2];
                    #pragma unroll
                    for (int nt = 0; nt < 2; ++nt) {
                        int nl = ph * 64 + (stB + nt) * 16 + col;
                        b[nt] = *(const bf16x8*)(sSb + nl * 272 + kt * 64 + quad * 16);
                    }
                    #pragma unroll
                    for (int mt = 0; mt < 4; ++mt)
                        #pragma unroll
                        for (int nt = 0; nt < 2; ++nt)
                            accT[ph][mt][nt] = __builtin_amdgcn_mfma_f32_16x16x32_bf16(a2[mt][kt], b[nt], accT[ph][mt][nt], 0, 0, 0);
                }
            }
            __syncthreads();   // S region reusable
        }
    }

    // ---- epilogue: per edge, acc -> sAcc, then out[l][c] = sum_s fg[l][s] * acc[s][c] ----
    for (int e = 0; e < 2; ++e) {
        #pragma unroll
        for (int mt = 0; mt < 4; ++mt) {
            int c = (htB + mt) * 16 + quad * 4;
            float4 gb = *(const float4*)(&sGB2[e][c]);
            #pragma unroll
            for (int nt = 0; nt < 2; ++nt) {
                int nl = (stB + nt) * 16 + col;
                float4 v;
                v.x = accT[e][mt][nt][0] + gb.x;
                v.y = accT[e][mt][nt][1] + gb.y;
                v.z = accT[e][mt][nt][2] + gb.z;
                v.w = accT[e][mt][nt][3] + gb.w;
                *(float4*)(sAcc + nl * 132 + c) = v;
            }
        }
        __syncthreads();
        for (int idx = tid; idx < 768; idx += 256) {
            int l = 1 + (idx >> 5);
            int c4 = (idx & 31) * 4;
            float4 a4 = {0.f, 0.f, 0.f, 0.f};
            const float* fgr = fg + l * 64;
            for (int s = 0; s < 64; ++s) {
                float f = fgr[s];
                const float* row = sAcc + s * 132 + c4;
                a4.x += f * row[0]; a4.y += f * row[1]; a4.z += f * row[2]; a4.w += f * row[3];
            }
            *(float4*)(out + (size_t)(e0 + e) * 3200 + l * 128 + c4) = a4;
        }
        __syncthreads();
    }
}

extern "C" void kernel_launch(void* const* d_in, const int* in_sizes, int n_in,
                              void* d_out, int out_size, void* d_ws, size_t ws_size,
                              hipStream_t stream) {
    (void)in_sizes; (void)n_in; (void)out_size; (void)ws_size;
    const float* message = (const float*)d_in[0];
    const float* gate    = (const float*)d_in[1];
    // d_in[2] = batch (unused by reference math)
    const float* ln1g = (const float*)d_in[3];
    const float* ln1b = (const float*)d_in[4];
    const float* wq   = (const float*)d_in[5];
    const float* bq   = (const float*)d_in[6];
    const float* wk   = (const float*)d_in[7];
    const float* bk   = (const float*)d_in[8];
    const float* wv   = (const float*)d_in[9];
    const float* bv   = (const float*)d_in[10];
    const float* nlg  = (const float*)d_in[11];
    const float* nlb  = (const float*)d_in[12];
    const float* fcw  = (const float*)d_in[13];
    const float* fcb  = (const float*)d_in[14];
    const float* elng = (const float*)d_in[15];
    const float* elnb = (const float*)d_in[16];
    const float* w1   = (const float*)d_in[17];
    const float* b1   = (const float*)d_in[18];
    const float* w2   = (const float*)d_in[19];
    const float* b2   = (const float*)d_in[20];
    const float* tg   = (const float*)d_in[21];
    const float* fg   = (const float*)d_in[22];
    const float* pe   = (const float*)d_in[23];
    float* ws  = (float*)d_ws;
    float* out = (float*)d_out;
    __hip_bfloat16* gtfp = (__hip_bfloat16*)(ws + OFF_GTF);
    __hip_bfloat16* wvtf = (__hip_bfloat16*)(ws + OFF_WVTF);
    __hip_bfloat16* tgf  = (__hip_bfloat16*)(ws + OFF_TGF);
    __hip_bfloat16* w1s  = (__hip_bfloat16*)(ws + OFF_W1S);
    __hip_bfloat16* w2s  = (__hip_bfloat16*)(ws + OFF_W2S);
    __hip_bfloat16* nout = (__hip_bfloat16*)(ws + OFF_NOUT);

    prep1<<<dim3(65), dim3(256), 0, stream>>>(wq, bq, wk, bk, pe, ws);
    prep2<<<dim3(8), dim3(256), 0, stream>>>(elnb, w1, b1, ws);
    prepSwz<<<dim3(4096), dim3(256), 0, stream>>>(elng, w1, w2, w1s, w2s);
    prepSwzA<<<dim3(136), dim3(256), 0, stream>>>(ws, wv, tg, gtfp, wvtf, tgf);
    kernA<<<dim3(E_), dim3(256), 0, stream>>>(message, ln1g, ln1b, bv, ws, gtfp, wvtf, tgf, nout);
    kernL0<<<dim3(E_), dim3(64), 0, stream>>>(message, nlg, nlb, fcw, fcb, out);
    kernC<<<dim3(E_ / 2), dim3(256), 0, stream>>>(nout, gate, w1s, w2s,
                                                  ws + OFF_B1P, b2, fg, out);
}